// Round 1
// baseline (795.524 us; speedup 1.0000x reference)
//
#include <hip/hip_runtime.h>
#include <math.h>

// Problem constants
// B=4, N=256, F=1024, H=16, K=128, HID=4096, TAB=32, D=64

// ---------------- TW precompute: dist_table[32,128] @ mlp_w1[0:128,16] -> [32,16]
__global__ __launch_bounds__(512) void tw_kernel(const float* __restrict__ table,
                                                 const float* __restrict__ w1,
                                                 float* __restrict__ tw) {
    int t = threadIdx.x;            // 512 threads: r in [0,32), o in [0,16)
    int r = t >> 4, o = t & 15;
    float a = 0.f;
    for (int k = 0; k < 128; ++k) a += table[r * 128 + k] * w1[k * 16 + o];
    tw[t] = a;
}

// ---------------- encoder: writes attn_bias TRANSPOSED as [B,H,N,N]
__global__ __launch_bounds__(256) void enc_kernel(
    const int* __restrict__ sp, const float* __restrict__ rd,
    const float* __restrict__ tw,
    const float* __restrict__ means, const float* __restrict__ stds,
    const float* __restrict__ gmul, const float* __restrict__ gbias,
    const float* __restrict__ w1, const float* __restrict__ b1,
    const float* __restrict__ w2, const float* __restrict__ b2,
    float* __restrict__ biasT)
{
    __shared__ float w1s[128][16];   // rd half of mlp_w1 (rows 128..255)
    __shared__ float w2s[16][16];
    __shared__ float b1s[16], b2s[16];
    __shared__ float meanS[128], istdS[128], coefS[128];
    int t = threadIdx.x;
    for (int i = t; i < 2048; i += 256) w1s[i >> 4][i & 15] = w1[2048 + i];
    w2s[t >> 4][t & 15] = w2[t];
    if (t < 16) { b1s[t] = b1[t]; b2s[t] = b2[t]; }
    if (t < 128) {
        float s = fabsf(stds[t]) + 0.01f;
        meanS[t] = means[t];
        istdS[t] = 1.f / s;
        coefS[t] = 1.f / (sqrtf(2.f * 3.14159f) * s);   // PI literal matches source
    }
    __syncthreads();

    // block = (b,i); thread = j
    int p = blockIdx.x * 256 + t;      // (b*256+i)*256 + j
    int idx = sp[p];
    float xv = gmul[0] * rd[p] + gbias[0];

    float acc[16];
    #pragma unroll
    for (int o = 0; o < 16; o++) acc[o] = b1s[o] + tw[idx * 16 + o];  // sp_emb@W1 via TW

    for (int k = 0; k < 128; k++) {
        float d = (xv - meanS[k]) * istdS[k];
        float g = coefS[k] * __expf(-0.5f * d * d);
        #pragma unroll
        for (int o = 0; o < 16; o++) acc[o] += g * w1s[k][o];
    }
    float h[16];
    #pragma unroll
    for (int o = 0; o < 16; o++) {
        float a = acc[o];
        h[o] = 0.5f * a * (1.f + erff(a * 0.70710678118f));  // exact GELU
    }
    float outv[16];
    #pragma unroll
    for (int o = 0; o < 16; o++) outv[o] = b2s[o];
    #pragma unroll
    for (int q = 0; q < 16; q++) {
        float hq = h[q];
        #pragma unroll
        for (int o = 0; o < 16; o++) outv[o] += hq * w2s[q][o];
    }
    int b = blockIdx.x >> 8, i = blockIdx.x & 255;
    #pragma unroll
    for (int hh = 0; hh < 16; hh++)
        biasT[(((b * 16 + hh) * 256 + i) << 8) + t] = outv[hh];  // coalesced over j=t
}

// ---------------- generic f32 tiled GEMM: C = epi(A[M,K]@B[K,N] + bias)
// epi: 0 = +bias ; 1 = +bias+add ; 2 = relu(+bias) ; 3 = qkv scatter [B,H,N,D] with alpha
__global__ __launch_bounds__(256) void gemm_kernel(
    const float* __restrict__ A, const float* __restrict__ Bm,
    const float* __restrict__ bias, const float* __restrict__ add,
    float* __restrict__ C, int M, int Nd, int Kd, int epi, float alpha)
{
    __shared__ float As[16][68];   // [kk][row], pad 68 -> <=2-way conflicts (free)
    __shared__ float Bs[16][68];   // [kk][col]
    int t = threadIdx.x;
    int tx = t & 15, ty = t >> 4;
    int row0 = blockIdx.y * 64, col0 = blockIdx.x * 64;
    float acc[4][4] = {{0.f}};

    int ar = t >> 2, ak = (t & 3) * 4;     // A loader: float4 along K
    int bk = t >> 4, bc = (t & 15) * 4;    // B loader: float4 along N

    for (int k0 = 0; k0 < Kd; k0 += 16) {
        float4 av = *reinterpret_cast<const float4*>(&A[(row0 + ar) * Kd + k0 + ak]);
        float4 bv = *reinterpret_cast<const float4*>(&Bm[(k0 + bk) * Nd + col0 + bc]);
        As[ak + 0][ar] = av.x; As[ak + 1][ar] = av.y;
        As[ak + 2][ar] = av.z; As[ak + 3][ar] = av.w;
        *reinterpret_cast<float4*>(&Bs[bk][bc]) = bv;
        __syncthreads();
        #pragma unroll
        for (int kk = 0; kk < 16; kk++) {
            float4 a4 = *reinterpret_cast<const float4*>(&As[kk][ty * 4]);
            float4 b4 = *reinterpret_cast<const float4*>(&Bs[kk][tx * 4]);
            float a[4] = {a4.x, a4.y, a4.z, a4.w};
            float b[4] = {b4.x, b4.y, b4.z, b4.w};
            #pragma unroll
            for (int i = 0; i < 4; i++)
                #pragma unroll
                for (int j = 0; j < 4; j++) acc[i][j] += a[i] * b[j];
        }
        __syncthreads();
    }

    #pragma unroll
    for (int i = 0; i < 4; i++) {
        int r = row0 + ty * 4 + i;
        #pragma unroll
        for (int j = 0; j < 4; j++) {
            int c = col0 + tx * 4 + j;
            float v = (acc[i][j] + bias[c]) * alpha;   // ref scales (x@W+b) by alpha
            if (epi == 1) v += add[r * Nd + c];
            else if (epi == 2) v = fmaxf(v, 0.f);
            if (epi == 3) {
                int bb = r >> 8, ii = r & 255, hh = c >> 6, dd = c & 63;
                C[(((bb * 16 + hh) * 256 + ii) << 6) + dd] = v;   // [B,H,N,D]
            } else {
                C[r * Nd + c] = v;
            }
        }
    }
}

// ---------------- scores + softmax: w[bh,i,j] = softmax_j(q[bh,i]·k[bh,j] + biasT[bh,i,j])
__global__ __launch_bounds__(256) void attn_sm_kernel(
    const float* __restrict__ q, const float* __restrict__ k,
    const float* __restrict__ biasT, float* __restrict__ w)
{
    int bi = blockIdx.x;           // bh*256 + i
    int bh = bi >> 8;
    __shared__ float qs[64];
    __shared__ float red[8];
    int t = threadIdx.x;           // t = j
    if (t < 64) qs[t] = q[bi * 64 + t];
    __syncthreads();
    const float4* kr = reinterpret_cast<const float4*>(k + (bh * 256 + t) * 64);
    float s = 0.f;
    #pragma unroll
    for (int d4 = 0; d4 < 16; d4++) {
        float4 kv = kr[d4];
        s += qs[d4 * 4 + 0] * kv.x + qs[d4 * 4 + 1] * kv.y
           + qs[d4 * 4 + 2] * kv.z + qs[d4 * 4 + 3] * kv.w;
    }
    s += biasT[bi * 256 + t];
    float m = s;
    #pragma unroll
    for (int off = 32; off; off >>= 1) m = fmaxf(m, __shfl_xor(m, off));
    if ((t & 63) == 0) red[t >> 6] = m;
    __syncthreads();
    m = fmaxf(fmaxf(red[0], red[1]), fmaxf(red[2], red[3]));
    float e = __expf(s - m);
    float sum = e;
    #pragma unroll
    for (int off = 32; off; off >>= 1) sum += __shfl_xor(sum, off);
    if ((t & 63) == 0) red[4 + (t >> 6)] = sum;
    __syncthreads();
    sum = red[4] + red[5] + red[6] + red[7];
    w[bi * 256 + t] = e / sum;
}

// ---------------- attn_out[b,i,h*64+d] = sum_j w[bh,i,j] * v[bh,j,d]
__global__ __launch_bounds__(64) void attn_av_kernel(
    const float* __restrict__ w, const float* __restrict__ v, float* __restrict__ out)
{
    int bi = blockIdx.x;           // bh*256 + i
    int bh = bi >> 8, i = bi & 255;
    int b = bh >> 4, h = bh & 15;
    __shared__ float wsm[256];
    int t = threadIdx.x;           // t = d
    #pragma unroll
    for (int j = 0; j < 4; j++) wsm[t + j * 64] = w[bi * 256 + t + j * 64];
    __syncthreads();
    float acc = 0.f;
    const float* vp = v + bh * 256 * 64 + t;
    #pragma unroll 8
    for (int j = 0; j < 256; j++) acc += wsm[j] * vp[j * 64];
    out[(b * 256 + i) * 1024 + h * 64 + t] = acc;
}

// ---------------- row LayerNorm over F=1024
__global__ __launch_bounds__(256) void ln_kernel(
    const float* __restrict__ x, const float* __restrict__ g,
    const float* __restrict__ bta, float* __restrict__ out)
{
    int row = blockIdx.x;
    int t = threadIdx.x;
    const float* xr = x + row * 1024;
    float v[4];
    float sum = 0.f;
    #pragma unroll
    for (int i = 0; i < 4; i++) { v[i] = xr[t + i * 256]; sum += v[i]; }
    __shared__ float red[8];
    #pragma unroll
    for (int off = 32; off; off >>= 1) sum += __shfl_xor(sum, off);
    if ((t & 63) == 0) red[t >> 6] = sum;
    __syncthreads();
    float mean = (red[0] + red[1] + red[2] + red[3]) * (1.f / 1024.f);
    float vs = 0.f;
    #pragma unroll
    for (int i = 0; i < 4; i++) { float d = v[i] - mean; vs += d * d; }
    #pragma unroll
    for (int off = 32; off; off >>= 1) vs += __shfl_xor(vs, off);
    if ((t & 63) == 0) red[4 + (t >> 6)] = vs;
    __syncthreads();
    float var = (red[4] + red[5] + red[6] + red[7]) * (1.f / 1024.f);
    float inv = rsqrtf(var + 1e-5f);
    #pragma unroll
    for (int i = 0; i < 4; i++) {
        int c = t + i * 256;
        out[row * 1024 + c] = (v[i] - mean) * inv * g[c] + bta[c];
    }
}

extern "C" void kernel_launch(void* const* d_in, const int* in_sizes, int n_in,
                              void* d_out, int out_size, void* d_ws, size_t ws_size,
                              hipStream_t stream)
{
    const float* nfeat  = (const float*)d_in[0];
    const int*   sp     = (const int*)  d_in[1];
    const float* rd     = (const float*)d_in[2];
    const float* table  = (const float*)d_in[3];
    const float* gmeans = (const float*)d_in[4];
    const float* gstds  = (const float*)d_in[5];
    const float* gmul   = (const float*)d_in[6];
    const float* gbias  = (const float*)d_in[7];
    const float* w1     = (const float*)d_in[8];
    const float* b1     = (const float*)d_in[9];
    const float* w2     = (const float*)d_in[10];
    const float* b2     = (const float*)d_in[11];
    const float* wq     = (const float*)d_in[12];
    const float* bq     = (const float*)d_in[13];
    const float* wk     = (const float*)d_in[14];
    const float* bk     = (const float*)d_in[15];
    const float* wv     = (const float*)d_in[16];
    const float* bv     = (const float*)d_in[17];
    const float* wo     = (const float*)d_in[18];
    const float* bo     = (const float*)d_in[19];
    const float* fw1    = (const float*)d_in[20];
    const float* fb1    = (const float*)d_in[21];
    const float* fw2    = (const float*)d_in[22];
    const float* fb2    = (const float*)d_in[23];
    const float* ln1g   = (const float*)d_in[24];
    const float* ln1b   = (const float*)d_in[25];
    const float* ln2g   = (const float*)d_in[26];
    const float* ln2b   = (const float*)d_in[27];

    float* ws     = (float*)d_ws;
    float* biasT  = ws;                     // 4,194,304 floats [B,H,N,N]
    float* qb     = ws + 4194304;           // 1,048,576  [B,H,N,D]
    float* kb     = qb + 1048576;
    float* vb     = kb + 1048576;
    float* wsm    = vb + 1048576;           // 4,194,304  [B,H,N,N]
    float* attno  = wsm + 4194304;          // 1,048,576  [B,N,F]
    float* y      = attno + 1048576;        // 1,048,576
    float* x1     = y + 1048576;            // 1,048,576
    float* tw     = x1 + 1048576;           // 512
    float* hidden = biasT;                  // reuse: biasT dead after attn_sm

    tw_kernel<<<1, 512, 0, stream>>>(table, w1, tw);
    enc_kernel<<<1024, 256, 0, stream>>>(sp, rd, tw, gmeans, gstds, gmul, gbias,
                                         w1, b1, w2, b2, biasT);
    dim3 g16(16, 16);
    gemm_kernel<<<g16, 256, 0, stream>>>(nfeat, wq, bq, nullptr, qb, 1024, 1024, 1024, 3, 8.0f);
    gemm_kernel<<<g16, 256, 0, stream>>>(nfeat, wk, bk, nullptr, kb, 1024, 1024, 1024, 3, 1.0f);
    gemm_kernel<<<g16, 256, 0, stream>>>(nfeat, wv, bv, nullptr, vb, 1024, 1024, 1024, 3, 1.0f);
    attn_sm_kernel<<<16384, 256, 0, stream>>>(qb, kb, biasT, wsm);
    attn_av_kernel<<<16384, 64, 0, stream>>>(wsm, vb, attno);
    gemm_kernel<<<g16, 256, 0, stream>>>(attno, wo, bo, nfeat, y, 1024, 1024, 1024, 1, 1.0f);
    ln_kernel<<<1024, 256, 0, stream>>>(y, ln1g, ln1b, x1);
    dim3 gf1(64, 16);
    gemm_kernel<<<gf1, 256, 0, stream>>>(x1, fw1, fb1, nullptr, hidden, 1024, 4096, 1024, 2, 1.0f);
    gemm_kernel<<<g16, 256, 0, stream>>>(hidden, fw2, fb2, x1, y, 1024, 1024, 4096, 1, 1.0f);
    ln_kernel<<<1024, 256, 0, stream>>>(y, ln2g, ln2b, (float*)d_out);
}

// Round 2
// 481.018 us; speedup vs baseline: 1.6538x; 1.6538x over previous
//
#include <hip/hip_runtime.h>
#include <hip/hip_bf16.h>
#include <math.h>

// B=4, N=256, F=1024, H=16, K=128, HID=4096, TAB=32, D=64
typedef __hip_bfloat16 bf16;
typedef float f32x4 __attribute__((ext_vector_type(4)));
typedef short bf16x8 __attribute__((ext_vector_type(8)));

#define AS1 __attribute__((address_space(1)))
#define AS3 __attribute__((address_space(3)))

// ---------------- TW precompute: dist_table[32,128] @ mlp_w1[0:128,16] -> [32,16]
__global__ __launch_bounds__(512) void tw_kernel(const float* __restrict__ table,
                                                 const float* __restrict__ w1,
                                                 float* __restrict__ tw) {
    int t = threadIdx.x;
    int r = t >> 4, o = t & 15;
    float a = 0.f;
    for (int k = 0; k < 128; ++k) a += table[r * 128 + k] * w1[k * 16 + o];
    tw[t] = a;
}

// ---------------- pack QKV bias into one [3072] array
__global__ __launch_bounds__(256) void bpack_kernel(const float* __restrict__ bq,
                                                    const float* __restrict__ bk,
                                                    const float* __restrict__ bv,
                                                    float* __restrict__ bqkv) {
    int i = blockIdx.x * 256 + threadIdx.x;
    bqkv[i] = i < 1024 ? bq[i] : (i < 2048 ? bk[i - 1024] : bv[i - 2048]);
}

// ---------------- f32 -> bf16 elementwise (n multiple of 1024)
__global__ __launch_bounds__(256) void cvt_kernel(const float* __restrict__ x,
                                                  bf16* __restrict__ y) {
    int i = (blockIdx.x * 256 + threadIdx.x) * 4;
    float4 v = *reinterpret_cast<const float4*>(x + i);
    y[i + 0] = (bf16)v.x; y[i + 1] = (bf16)v.y;
    y[i + 2] = (bf16)v.z; y[i + 3] = (bf16)v.w;
}

// ---------------- transpose+convert: W[Kd][Nd] f32 -> WT[Nd][Kd] bf16
__global__ __launch_bounds__(256) void wt_kernel(const float* __restrict__ W,
                                                 bf16* __restrict__ WT, int Kd, int Nd) {
    __shared__ float tile[32][33];
    int t = threadIdx.x;
    int n0 = blockIdx.x * 32, k0 = blockIdx.y * 32;
    int tx = t & 31, ty = t >> 5;
    #pragma unroll
    for (int p = 0; p < 4; p++)
        tile[ty + p * 8][tx] = W[(k0 + ty + p * 8) * Nd + n0 + tx];
    __syncthreads();
    #pragma unroll
    for (int p = 0; p < 4; p++)
        WT[(n0 + ty + p * 8) * Kd + k0 + tx] = (bf16)tile[tx][ty + p * 8];
}

// ---------------- encoder: writes attn_bias TRANSPOSED as [B,H,N,N], bf16
__global__ __launch_bounds__(256) void enc_kernel(
    const int* __restrict__ sp, const float* __restrict__ rd,
    const float* __restrict__ tw,
    const float* __restrict__ means, const float* __restrict__ stds,
    const float* __restrict__ gmul, const float* __restrict__ gbias,
    const float* __restrict__ w1, const float* __restrict__ b1,
    const float* __restrict__ w2, const float* __restrict__ b2,
    bf16* __restrict__ biasT)
{
    __shared__ float w1s[128][16];
    __shared__ float w2s[16][16];
    __shared__ float b1s[16], b2s[16];
    __shared__ float meanS[128], istdS[128], coefS[128];
    int t = threadIdx.x;
    for (int i = t; i < 2048; i += 256) w1s[i >> 4][i & 15] = w1[2048 + i];
    w2s[t >> 4][t & 15] = w2[t];
    if (t < 16) { b1s[t] = b1[t]; b2s[t] = b2[t]; }
    if (t < 128) {
        float s = fabsf(stds[t]) + 0.01f;
        meanS[t] = means[t];
        istdS[t] = 1.f / s;
        coefS[t] = 1.f / (sqrtf(2.f * 3.14159f) * s);
    }
    __syncthreads();

    int p = blockIdx.x * 256 + t;
    int idx = sp[p];
    float xv = gmul[0] * rd[p] + gbias[0];

    float acc[16];
    #pragma unroll
    for (int o = 0; o < 16; o++) acc[o] = b1s[o] + tw[idx * 16 + o];

    for (int k = 0; k < 128; k++) {
        float d = (xv - meanS[k]) * istdS[k];
        float g = coefS[k] * __expf(-0.5f * d * d);
        #pragma unroll
        for (int o = 0; o < 16; o++) acc[o] += g * w1s[k][o];
    }
    float h[16];
    #pragma unroll
    for (int o = 0; o < 16; o++) {
        float a = acc[o];
        h[o] = 0.5f * a * (1.f + erff(a * 0.70710678118f));
    }
    float outv[16];
    #pragma unroll
    for (int o = 0; o < 16; o++) outv[o] = b2s[o];
    #pragma unroll
    for (int q = 0; q < 16; q++) {
        float hq = h[q];
        #pragma unroll
        for (int o = 0; o < 16; o++) outv[o] += hq * w2s[q][o];
    }
    int b = blockIdx.x >> 8, i = blockIdx.x & 255;
    #pragma unroll
    for (int hh = 0; hh < 16; hh++)
        biasT[(((b * 16 + hh) * 256 + i) << 8) + t] = (bf16)outv[hh];
}

// ---------------- bf16 MFMA GEMM: C = epi(A[M,K] @ BT[N,K]^T + bias)
// 128x128 tile, BK=32, 4 waves (2x2), each wave 64x64 = 4x4 frags of 16x16x32.
// LDS chunk-major: addr = chunk(c)*2048 + row*16, c = k-octet. Staged via
// global_load_lds width-16 (linear dest = wave-uniform base + lane*16).
// epi: 0=+bias f32 ; 1=+bias+add f32 ; 2=relu(+bias) bf16 ; 3=qkv scatter f32
__global__ __launch_bounds__(256, 2) void gemm_bf16(
    const bf16* __restrict__ A, const bf16* __restrict__ BT,
    const float* __restrict__ bias, const float* __restrict__ add,
    void* __restrict__ C, int M, int Nd, int Kd, int epi)
{
    __shared__ __align__(16) char smem[16384];   // As 8KB | Bs 8KB
    int t = threadIdx.x;
    int w = t >> 6, l = t & 63;
    int row0 = blockIdx.y * 128, col0 = blockIdx.x * 128;
    int wr = w >> 1, wc = w & 1;

    f32x4 acc[4][4];
    #pragma unroll
    for (int i = 0; i < 4; i++)
        #pragma unroll
        for (int j = 0; j < 4; j++) acc[i][j] = (f32x4){0.f, 0.f, 0.f, 0.f};

    // staging: thread t, issue p covers chunk c = 2p + (t>=128), row = t&127
    int sr = t & 127;
    int sc = t >> 7;
    const bf16* Asrc = A + (row0 + sr) * Kd + sc * 8;
    const bf16* Bsrc = BT + (col0 + sr) * Kd + sc * 8;
    char* AsW = smem + (t & 192) * 16;          // wave-uniform base (w*1024)
    char* BsW = AsW + 8192;

    int lr = l & 15, lc = l >> 4;
    const char* aRd = smem + lc * 2048 + (wr * 64 + lr) * 16;
    const char* bRd = smem + 8192 + lc * 2048 + (wc * 64 + lr) * 16;

    for (int k0 = 0; k0 < Kd; k0 += 32) {
        #pragma unroll
        for (int p = 0; p < 2; p++) {
            __builtin_amdgcn_global_load_lds((const AS1 void*)(Asrc + k0 + p * 16),
                                             (AS3 void*)(AsW + p * 4096), 16, 0, 0);
            __builtin_amdgcn_global_load_lds((const AS1 void*)(Bsrc + k0 + p * 16),
                                             (AS3 void*)(BsW + p * 4096), 16, 0, 0);
        }
        __syncthreads();
        bf16x8 af[4], bf[4];
        #pragma unroll
        for (int i = 0; i < 4; i++) af[i] = *(const bf16x8*)(aRd + i * 256);
        #pragma unroll
        for (int j = 0; j < 4; j++) bf[j] = *(const bf16x8*)(bRd + j * 256);
        #pragma unroll
        for (int i = 0; i < 4; i++)
            #pragma unroll
            for (int j = 0; j < 4; j++)
                acc[i][j] = __builtin_amdgcn_mfma_f32_16x16x32_bf16(af[i], bf[j], acc[i][j], 0, 0, 0);
        __syncthreads();
    }

    // epilogue: C row = row0+wr*64+i*16+(l>>4)*4+q ; col = col0+wc*64+j*16+(l&15)
    #pragma unroll
    for (int i = 0; i < 4; i++) {
        int rb = row0 + wr * 64 + i * 16 + lc * 4;
        #pragma unroll
        for (int j = 0; j < 4; j++) {
            int cc = col0 + wc * 64 + j * 16 + lr;
            float bsv = bias[cc];
            f32x4 v = acc[i][j];
            #pragma unroll
            for (int q = 0; q < 4; q++) {
                int r = rb + q;
                float x = v[q] + bsv;
                if (epi == 0) {
                    ((float*)C)[r * Nd + cc] = x;
                } else if (epi == 1) {
                    ((float*)C)[r * Nd + cc] = x + add[r * Nd + cc];
                } else if (epi == 2) {
                    ((bf16*)C)[r * Nd + cc] = (bf16)fmaxf(x, 0.f);
                } else {
                    int sel = cc >> 10, ccc = cc & 1023;
                    if (sel == 0) x *= 8.0f;                       // q * sqrt(D)
                    int hh = ccc >> 6, dd = ccc & 63;
                    ((float*)C)[sel * 1048576 +
                                (((r >> 8) * 16 + hh) * 256 + (r & 255)) * 64 + dd] = x;
                }
            }
        }
    }
}

// ---------------- scores + softmax: wsm[bh,i,j] = softmax_j(q·k + biasT)
__global__ __launch_bounds__(256) void attn_sm_kernel(
    const float* __restrict__ q, const float* __restrict__ k,
    const bf16* __restrict__ biasT, bf16* __restrict__ w)
{
    int bi = blockIdx.x;           // bh*256 + i
    int bh = bi >> 8;
    __shared__ float qs[64];
    __shared__ float red[8];
    int t = threadIdx.x;           // t = j
    if (t < 64) qs[t] = q[bi * 64 + t];
    __syncthreads();
    const float4* kr = reinterpret_cast<const float4*>(k + (bh * 256 + t) * 64);
    float s = 0.f;
    #pragma unroll
    for (int d4 = 0; d4 < 16; d4++) {
        float4 kv = kr[d4];
        s += qs[d4 * 4 + 0] * kv.x + qs[d4 * 4 + 1] * kv.y
           + qs[d4 * 4 + 2] * kv.z + qs[d4 * 4 + 3] * kv.w;
    }
    s += __bfloat162float(biasT[bi * 256 + t]);
    float m = s;
    #pragma unroll
    for (int off = 32; off; off >>= 1) m = fmaxf(m, __shfl_xor(m, off));
    if ((t & 63) == 0) red[t >> 6] = m;
    __syncthreads();
    m = fmaxf(fmaxf(red[0], red[1]), fmaxf(red[2], red[3]));
    float e = __expf(s - m);
    float sum = e;
    #pragma unroll
    for (int off = 32; off; off >>= 1) sum += __shfl_xor(sum, off);
    if ((t & 63) == 0) red[4 + (t >> 6)] = sum;
    __syncthreads();
    sum = red[4] + red[5] + red[6] + red[7];
    w[bi * 256 + t] = (bf16)(e / sum);
}

// ---------------- attn_out[b,i,h*64+d] = sum_j wsm[bh,i,j] * v[bh,j,d]  (bf16 out)
__global__ __launch_bounds__(64) void attn_av_kernel(
    const bf16* __restrict__ w, const float* __restrict__ v, bf16* __restrict__ out)
{
    int bi = blockIdx.x;
    int bh = bi >> 8, i = bi & 255;
    int b = bh >> 4, h = bh & 15;
    __shared__ float wsm[256];
    int t = threadIdx.x;           // t = d
    #pragma unroll
    for (int j = 0; j < 4; j++) wsm[t + j * 64] = __bfloat162float(w[bi * 256 + t + j * 64]);
    __syncthreads();
    float acc = 0.f;
    const float* vp = v + bh * 256 * 64 + t;
    #pragma unroll 8
    for (int j = 0; j < 256; j++) acc += wsm[j] * vp[j * 64];
    out[(b * 256 + i) * 1024 + h * 64 + t] = (bf16)acc;
}

// ---------------- row LayerNorm over F=1024; optional bf16 secondary output
__global__ __launch_bounds__(256) void ln_kernel(
    const float* __restrict__ x, const float* __restrict__ g,
    const float* __restrict__ bta, float* __restrict__ out, bf16* __restrict__ ob)
{
    int row = blockIdx.x;
    int t = threadIdx.x;
    const float* xr = x + row * 1024;
    float v[4];
    float sum = 0.f;
    #pragma unroll
    for (int i = 0; i < 4; i++) { v[i] = xr[t + i * 256]; sum += v[i]; }
    __shared__ float red[8];
    #pragma unroll
    for (int off = 32; off; off >>= 1) sum += __shfl_xor(sum, off);
    if ((t & 63) == 0) red[t >> 6] = sum;
    __syncthreads();
    float mean = (red[0] + red[1] + red[2] + red[3]) * (1.f / 1024.f);
    float vs = 0.f;
    #pragma unroll
    for (int i = 0; i < 4; i++) { float d = v[i] - mean; vs += d * d; }
    #pragma unroll
    for (int off = 32; off; off >>= 1) vs += __shfl_xor(vs, off);
    if ((t & 63) == 0) red[4 + (t >> 6)] = vs;
    __syncthreads();
    float var = (red[4] + red[5] + red[6] + red[7]) * (1.f / 1024.f);
    float inv = rsqrtf(var + 1e-5f);
    #pragma unroll
    for (int i = 0; i < 4; i++) {
        int c = t + i * 256;
        float o = (v[i] - mean) * inv * g[c] + bta[c];
        out[row * 1024 + c] = o;
        if (ob) ob[row * 1024 + c] = (bf16)o;
    }
}

extern "C" void kernel_launch(void* const* d_in, const int* in_sizes, int n_in,
                              void* d_out, int out_size, void* d_ws, size_t ws_size,
                              hipStream_t stream)
{
    const float* nfeat  = (const float*)d_in[0];
    const int*   sp     = (const int*)  d_in[1];
    const float* rd     = (const float*)d_in[2];
    const float* table  = (const float*)d_in[3];
    const float* gmeans = (const float*)d_in[4];
    const float* gstds  = (const float*)d_in[5];
    const float* gmul   = (const float*)d_in[6];
    const float* gbias  = (const float*)d_in[7];
    const float* w1     = (const float*)d_in[8];
    const float* b1     = (const float*)d_in[9];
    const float* w2     = (const float*)d_in[10];
    const float* b2     = (const float*)d_in[11];
    const float* wq     = (const float*)d_in[12];
    const float* bq     = (const float*)d_in[13];
    const float* wk     = (const float*)d_in[14];
    const float* bk     = (const float*)d_in[15];
    const float* wv     = (const float*)d_in[16];
    const float* bv     = (const float*)d_in[17];
    const float* wo     = (const float*)d_in[18];
    const float* bo     = (const float*)d_in[19];
    const float* fw1    = (const float*)d_in[20];
    const float* fb1    = (const float*)d_in[21];
    const float* fw2    = (const float*)d_in[22];
    const float* fb2    = (const float*)d_in[23];
    const float* ln1g   = (const float*)d_in[24];
    const float* ln1b   = (const float*)d_in[25];
    const float* ln2g   = (const float*)d_in[26];
    const float* ln2b   = (const float*)d_in[27];

    const size_t MB = 1 << 20;
    char* cws = (char*)d_ws;
    bf16*  biasT   = (bf16*)(cws);             // 8MB  [B,H,N,N]; reused as hiddenb
    bf16*  wsmB    = (bf16*)(cws + 8 * MB);    // 8MB  [B,H,N,N]
    float* qb      = (float*)(cws + 16 * MB);  // 4MB  [B,H,N,D]
    float* kb      = (float*)(cws + 20 * MB);  // 4MB
    float* vb      = (float*)(cws + 24 * MB);  // 4MB
    float* y       = (float*)(cws + 28 * MB);  // 4MB
    float* x1      = (float*)(cws + 32 * MB);  // 4MB
    bf16*  wbuf    = (bf16*)(cws + 36 * MB);   // 8MB  (reused per weight)
    bf16*  nfeatb  = (bf16*)(cws + 44 * MB);   // 2MB
    bf16*  x1b     = (bf16*)(cws + 46 * MB);   // 2MB
    bf16*  attnob  = (bf16*)(cws + 48 * MB);   // 2MB
    float* bqkv    = (float*)(cws + 50 * MB);  // 12KB
    float* tw      = (float*)(cws + 50 * MB + 16384);
    bf16*  hiddenb = biasT;                    // [1024][4096] bf16

    tw_kernel<<<1, 512, 0, stream>>>(table, w1, tw);
    bpack_kernel<<<12, 256, 0, stream>>>(bq, bk, bv, bqkv);
    cvt_kernel<<<1024, 256, 0, stream>>>(nfeat, nfeatb);
    enc_kernel<<<1024, 256, 0, stream>>>(sp, rd, tw, gmeans, gstds, gmul, gbias,
                                         w1, b1, w2, b2, biasT);

    // QKV fused: BT = [wqT | wkT | wvT] rows 0..3071
    wt_kernel<<<dim3(32, 32), 256, 0, stream>>>(wq, wbuf, 1024, 1024);
    wt_kernel<<<dim3(32, 32), 256, 0, stream>>>(wk, wbuf + 1048576, 1024, 1024);
    wt_kernel<<<dim3(32, 32), 256, 0, stream>>>(wv, wbuf + 2097152, 1024, 1024);
    gemm_bf16<<<dim3(24, 8), 256, 0, stream>>>(nfeatb, wbuf, bqkv, nullptr, qb,
                                               1024, 3072, 1024, 3);

    attn_sm_kernel<<<16384, 256, 0, stream>>>(qb, kb, biasT, wsmB);
    attn_av_kernel<<<16384, 64, 0, stream>>>(wsmB, vb, attnob);

    wt_kernel<<<dim3(32, 32), 256, 0, stream>>>(wo, wbuf, 1024, 1024);
    gemm_bf16<<<dim3(8, 8), 256, 0, stream>>>(attnob, wbuf, bo, nfeat, y,
                                              1024, 1024, 1024, 1);
    ln_kernel<<<1024, 256, 0, stream>>>(y, ln1g, ln1b, x1, x1b);

    wt_kernel<<<dim3(128, 32), 256, 0, stream>>>(fw1, wbuf, 1024, 4096);
    gemm_bf16<<<dim3(32, 8), 256, 0, stream>>>(x1b, wbuf, fb1, nullptr, hiddenb,
                                               1024, 4096, 1024, 2);

    wt_kernel<<<dim3(32, 128), 256, 0, stream>>>(fw2, wbuf, 4096, 1024);
    gemm_bf16<<<dim3(8, 8), 256, 0, stream>>>(hiddenb, wbuf, fb2, x1, y,
                                              1024, 1024, 4096, 1);

    ln_kernel<<<1024, 256, 0, stream>>>(y, ln2g, ln2b, (float*)d_out, nullptr);
}

// Round 3
// 336.151 us; speedup vs baseline: 2.3666x; 1.4310x over previous
//
#include <hip/hip_runtime.h>
#include <hip/hip_bf16.h>
#include <math.h>

// B=4, N=256, F=1024, H=16, K=128, HID=4096, TAB=32, D=64
typedef __hip_bfloat16 bf16;
typedef float f32x4 __attribute__((ext_vector_type(4)));
typedef short bf16x8 __attribute__((ext_vector_type(8)));

#define AS1 __attribute__((address_space(1)))
#define AS3 __attribute__((address_space(3)))

// ---------------- TW precompute: dist_table[32,128] @ mlp_w1[0:128,16] -> [32,16]
__global__ __launch_bounds__(512) void tw_kernel(const float* __restrict__ table,
                                                 const float* __restrict__ w1,
                                                 float* __restrict__ tw) {
    int t = threadIdx.x;
    int r = t >> 4, o = t & 15;
    float a = 0.f;
    for (int k = 0; k < 128; ++k) a += table[r * 128 + k] * w1[k * 16 + o];
    tw[t] = a;
}

// ---------------- pack QKV bias into one [3072] array
__global__ __launch_bounds__(256) void bpack_kernel(const float* __restrict__ bq,
                                                    const float* __restrict__ bk,
                                                    const float* __restrict__ bv,
                                                    float* __restrict__ bqkv) {
    int i = blockIdx.x * 256 + threadIdx.x;
    bqkv[i] = i < 1024 ? bq[i] : (i < 2048 ? bk[i - 1024] : bv[i - 2048]);
}

// ---------------- f32 -> bf16 elementwise
__global__ __launch_bounds__(256) void cvt_kernel(const float* __restrict__ x,
                                                  bf16* __restrict__ y) {
    int i = (blockIdx.x * 256 + threadIdx.x) * 4;
    float4 v = *reinterpret_cast<const float4*>(x + i);
    y[i + 0] = (bf16)v.x; y[i + 1] = (bf16)v.y;
    y[i + 2] = (bf16)v.z; y[i + 3] = (bf16)v.w;
}

// ---------------- transpose+convert: W[Kd][Nd] f32 -> WT[Nd][Kd] bf16
__global__ __launch_bounds__(256) void wt_kernel(const float* __restrict__ W,
                                                 bf16* __restrict__ WT, int Kd, int Nd) {
    __shared__ float tile[32][33];
    int t = threadIdx.x;
    int n0 = blockIdx.x * 32, k0 = blockIdx.y * 32;
    int tx = t & 31, ty = t >> 5;
    #pragma unroll
    for (int p = 0; p < 4; p++)
        tile[ty + p * 8][tx] = W[(k0 + ty + p * 8) * Nd + n0 + tx];
    __syncthreads();
    #pragma unroll
    for (int p = 0; p < 4; p++)
        WT[(n0 + ty + p * 8) * Kd + k0 + tx] = (bf16)tile[tx][ty + p * 8];
}

// ---------------- encoder: writes attn_bias TRANSPOSED as [B,H,N,N], bf16
__global__ __launch_bounds__(256) void enc_kernel(
    const int* __restrict__ sp, const float* __restrict__ rd,
    const float* __restrict__ tw,
    const float* __restrict__ means, const float* __restrict__ stds,
    const float* __restrict__ gmul, const float* __restrict__ gbias,
    const float* __restrict__ w1, const float* __restrict__ b1,
    const float* __restrict__ w2, const float* __restrict__ b2,
    bf16* __restrict__ biasT)
{
    __shared__ float w1s[128][16];
    __shared__ float w2s[16][16];
    __shared__ float b1s[16], b2s[16];
    __shared__ float meanS[128], istdS[128], coefS[128];
    int t = threadIdx.x;
    for (int i = t; i < 2048; i += 256) w1s[i >> 4][i & 15] = w1[2048 + i];
    w2s[t >> 4][t & 15] = w2[t];
    if (t < 16) { b1s[t] = b1[t]; b2s[t] = b2[t]; }
    if (t < 128) {
        float s = fabsf(stds[t]) + 0.01f;
        meanS[t] = means[t];
        istdS[t] = 1.f / s;
        coefS[t] = 1.f / (sqrtf(2.f * 3.14159f) * s);
    }
    __syncthreads();

    int p = blockIdx.x * 256 + t;
    int idx = sp[p];
    float xv = gmul[0] * rd[p] + gbias[0];

    float acc[16];
    #pragma unroll
    for (int o = 0; o < 16; o++) acc[o] = b1s[o] + tw[idx * 16 + o];

    for (int k = 0; k < 128; k++) {
        float d = (xv - meanS[k]) * istdS[k];
        float g = coefS[k] * __expf(-0.5f * d * d);
        #pragma unroll
        for (int o = 0; o < 16; o++) acc[o] += g * w1s[k][o];
    }
    float h[16];
    #pragma unroll
    for (int o = 0; o < 16; o++) {
        float a = acc[o];
        h[o] = 0.5f * a * (1.f + erff(a * 0.70710678118f));
    }
    float outv[16];
    #pragma unroll
    for (int o = 0; o < 16; o++) outv[o] = b2s[o];
    #pragma unroll
    for (int q = 0; q < 16; q++) {
        float hq = h[q];
        #pragma unroll
        for (int o = 0; o < 16; o++) outv[o] += hq * w2s[q][o];
    }
    int b = blockIdx.x >> 8, i = blockIdx.x & 255;
    #pragma unroll
    for (int hh = 0; hh < 16; hh++)
        biasT[(((b * 16 + hh) * 256 + i) << 8) + t] = (bf16)outv[hh];
}

// ---------------- bf16 MFMA GEMM (128x128 tile, BK=32, 4 waves 2x2)
// epi: 0=+bias f32 ; 1=+bias+add f32 ; 2=relu(+bias) bf16 ;
// epi 3 = fused QKV epilogue into bf16: q*8 [B,H,N,D] | k [B,H,N,D] | v^T [B,H,D,N]
__global__ __launch_bounds__(256, 2) void gemm_bf16(
    const bf16* __restrict__ A, const bf16* __restrict__ BT,
    const float* __restrict__ bias, const float* __restrict__ add,
    void* __restrict__ C, int M, int Nd, int Kd, int epi)
{
    __shared__ __align__(16) char smem[16384];   // As 8KB | Bs 8KB
    int t = threadIdx.x;
    int w = t >> 6, l = t & 63;
    int row0 = blockIdx.y * 128, col0 = blockIdx.x * 128;
    int wr = w >> 1, wc = w & 1;

    f32x4 acc[4][4];
    #pragma unroll
    for (int i = 0; i < 4; i++)
        #pragma unroll
        for (int j = 0; j < 4; j++) acc[i][j] = (f32x4){0.f, 0.f, 0.f, 0.f};

    int sr = t & 127;
    int sc = t >> 7;
    const bf16* Asrc = A + (row0 + sr) * Kd + sc * 8;
    const bf16* Bsrc = BT + (col0 + sr) * Kd + sc * 8;
    char* AsW = smem + (t & 192) * 16;
    char* BsW = AsW + 8192;

    int lr = l & 15, lc = l >> 4;
    const char* aRd = smem + lc * 2048 + (wr * 64 + lr) * 16;
    const char* bRd = smem + 8192 + lc * 2048 + (wc * 64 + lr) * 16;

    for (int k0 = 0; k0 < Kd; k0 += 32) {
        #pragma unroll
        for (int p = 0; p < 2; p++) {
            __builtin_amdgcn_global_load_lds((const AS1 void*)(Asrc + k0 + p * 16),
                                             (AS3 void*)(AsW + p * 4096), 16, 0, 0);
            __builtin_amdgcn_global_load_lds((const AS1 void*)(Bsrc + k0 + p * 16),
                                             (AS3 void*)(BsW + p * 4096), 16, 0, 0);
        }
        __syncthreads();
        bf16x8 af[4], bfr[4];
        #pragma unroll
        for (int i = 0; i < 4; i++) af[i] = *(const bf16x8*)(aRd + i * 256);
        #pragma unroll
        for (int j = 0; j < 4; j++) bfr[j] = *(const bf16x8*)(bRd + j * 256);
        #pragma unroll
        for (int i = 0; i < 4; i++)
            #pragma unroll
            for (int j = 0; j < 4; j++)
                acc[i][j] = __builtin_amdgcn_mfma_f32_16x16x32_bf16(af[i], bfr[j], acc[i][j], 0, 0, 0);
        __syncthreads();
    }

    #pragma unroll
    for (int i = 0; i < 4; i++) {
        int rb = row0 + wr * 64 + i * 16 + lc * 4;
        #pragma unroll
        for (int j = 0; j < 4; j++) {
            int cc = col0 + wc * 64 + j * 16 + lr;
            float bsv = bias[cc];
            f32x4 v = acc[i][j];
            #pragma unroll
            for (int q = 0; q < 4; q++) {
                int r = rb + q;
                float x = v[q] + bsv;
                if (epi == 0) {
                    ((float*)C)[r * Nd + cc] = x;
                } else if (epi == 1) {
                    ((float*)C)[r * Nd + cc] = x + add[r * Nd + cc];
                } else if (epi == 2) {
                    ((bf16*)C)[r * Nd + cc] = (bf16)fmaxf(x, 0.f);
                } else {
                    bf16* Cb = (bf16*)C;
                    int sel = cc >> 10, ccc = cc & 1023;
                    int hh = ccc >> 6, dd = ccc & 63;
                    int bb = r >> 8, ii = r & 255;
                    if (sel == 0)
                        Cb[(((bb * 16 + hh) * 256 + ii) << 6) + dd] = (bf16)(x * 8.0f);
                    else if (sel == 1)
                        Cb[1048576 + (((bb * 16 + hh) * 256 + ii) << 6) + dd] = (bf16)x;
                    else
                        Cb[2097152 + ((((bb * 16 + hh) << 6) + dd) << 8) + ii] = (bf16)x;
                }
            }
        }
    }
}

// ---------------- fused attention: per block = (bh, i-quarter of 64 rows)
// wave w owns 16 rows. S=Q@K^T (frags direct from global) + bias, in-register
// softmax, P->LDS (chunk-major), O=P@V via VT [B,H,D,N]. Out bf16 [B,N,F].
__global__ __launch_bounds__(256) void flash_kernel(
    const bf16* __restrict__ Qb, const bf16* __restrict__ Kb,
    const bf16* __restrict__ VT, const bf16* __restrict__ biasT,
    bf16* __restrict__ out)
{
    __shared__ __align__(16) char pls[32768];   // 4 waves x 8KB P tiles
    int t = threadIdx.x;
    int w = t >> 6, l = t & 63;
    int lr = l & 15, hi = l >> 4;
    int bh = blockIdx.x >> 2, iq = blockIdx.x & 3;
    int b = bh >> 4, h = bh & 15;
    int i0 = iq * 64 + w * 16;

    // Q A-frags: row = i0+lr, k-octet = hi (2 k-steps over D=64)
    const bf16* Qp = Qb + (bh * 256 + i0 + lr) * 64 + hi * 8;
    bf16x8 qf0 = *(const bf16x8*)(Qp);
    bf16x8 qf1 = *(const bf16x8*)(Qp + 32);

    f32x4 acc[16];
    #pragma unroll
    for (int f = 0; f < 16; f++) acc[f] = (f32x4){0.f, 0.f, 0.f, 0.f};

    // S = Q K^T : 16 j-frags
    const bf16* Kp = Kb + (bh * 256 + lr) * 64 + hi * 8;
    #pragma unroll
    for (int f = 0; f < 16; f++) {
        bf16x8 kf0 = *(const bf16x8*)(Kp + f * 1024);
        bf16x8 kf1 = *(const bf16x8*)(Kp + f * 1024 + 32);
        acc[f] = __builtin_amdgcn_mfma_f32_16x16x32_bf16(qf0, kf0, acc[f], 0, 0, 0);
        acc[f] = __builtin_amdgcn_mfma_f32_16x16x32_bf16(qf1, kf1, acc[f], 0, 0, 0);
    }

    // + bias (C-layout: row=i0+hi*4+q, col=f*16+lr)
    const bf16* bp = biasT + (bh * 256 + i0 + hi * 4) * 256 + lr;
    #pragma unroll
    for (int f = 0; f < 16; f++)
        #pragma unroll
        for (int q = 0; q < 4; q++)
            acc[f][q] += __bfloat162float(bp[q * 256 + f * 16]);

    // in-register softmax over 256 j per row
    float inv[4];
    #pragma unroll
    for (int q = 0; q < 4; q++) {
        float m = acc[0][q];
        #pragma unroll
        for (int f = 1; f < 16; f++) m = fmaxf(m, acc[f][q]);
        #pragma unroll
        for (int msk = 1; msk < 16; msk <<= 1) m = fmaxf(m, __shfl_xor(m, msk));
        float s = 0.f;
        #pragma unroll
        for (int f = 0; f < 16; f++) {
            float e = __expf(acc[f][q] - m);
            acc[f][q] = e;
            s += e;
        }
        #pragma unroll
        for (int msk = 1; msk < 16; msk <<= 1) s += __shfl_xor(s, msk);
        inv[q] = 1.f / s;
    }

    // P -> LDS, chunk-major [32 chunks][16 rows][16B]
    char* Pw = pls + w * 8192;
    #pragma unroll
    for (int f = 0; f < 16; f++) {
        int j = f * 16 + lr;
        int c = j >> 3, jo = j & 7;
        #pragma unroll
        for (int q = 0; q < 4; q++)
            *(bf16*)(Pw + c * 256 + (hi * 4 + q) * 16 + jo * 2) = (bf16)(acc[f][q] * inv[q]);
    }
    __syncthreads();

    // O = P @ V : A-frag row=lr, chunk=ks*4+hi ; B-frag col d=n*16+lr from VT
    const char* Pr = pls + w * 8192 + hi * 256 + lr * 16;
    const bf16* Vp = VT + (bh * 64 + lr) * 256 + hi * 8;
    #pragma unroll
    for (int n = 0; n < 4; n++) {
        f32x4 o = (f32x4){0.f, 0.f, 0.f, 0.f};
        #pragma unroll
        for (int ks = 0; ks < 8; ks++) {
            bf16x8 pa = *(const bf16x8*)(Pr + ks * 1024);
            bf16x8 vb = *(const bf16x8*)(Vp + n * 4096 + ks * 32);
            o = __builtin_amdgcn_mfma_f32_16x16x32_bf16(pa, vb, o, 0, 0, 0);
        }
        #pragma unroll
        for (int q = 0; q < 4; q++)
            out[(b * 256 + i0 + hi * 4 + q) * 1024 + h * 64 + n * 16 + lr] = (bf16)o[q];
    }
}

// ---------------- row LayerNorm over F=1024; optional bf16 secondary output
__global__ __launch_bounds__(256) void ln_kernel(
    const float* __restrict__ x, const float* __restrict__ g,
    const float* __restrict__ bta, float* __restrict__ out, bf16* __restrict__ ob)
{
    int row = blockIdx.x;
    int t = threadIdx.x;
    const float* xr = x + row * 1024;
    float v[4];
    float sum = 0.f;
    #pragma unroll
    for (int i = 0; i < 4; i++) { v[i] = xr[t + i * 256]; sum += v[i]; }
    __shared__ float red[8];
    #pragma unroll
    for (int off = 32; off; off >>= 1) sum += __shfl_xor(sum, off);
    if ((t & 63) == 0) red[t >> 6] = sum;
    __syncthreads();
    float mean = (red[0] + red[1] + red[2] + red[3]) * (1.f / 1024.f);
    float vs = 0.f;
    #pragma unroll
    for (int i = 0; i < 4; i++) { float d = v[i] - mean; vs += d * d; }
    #pragma unroll
    for (int off = 32; off; off >>= 1) vs += __shfl_xor(vs, off);
    if ((t & 63) == 0) red[4 + (t >> 6)] = vs;
    __syncthreads();
    float var = (red[4] + red[5] + red[6] + red[7]) * (1.f / 1024.f);
    float invs = rsqrtf(var + 1e-5f);
    #pragma unroll
    for (int i = 0; i < 4; i++) {
        int c = t + i * 256;
        float o = (v[i] - mean) * invs * g[c] + bta[c];
        out[row * 1024 + c] = o;
        if (ob) ob[row * 1024 + c] = (bf16)o;
    }
}

extern "C" void kernel_launch(void* const* d_in, const int* in_sizes, int n_in,
                              void* d_out, int out_size, void* d_ws, size_t ws_size,
                              hipStream_t stream)
{
    const float* nfeat  = (const float*)d_in[0];
    const int*   sp     = (const int*)  d_in[1];
    const float* rd     = (const float*)d_in[2];
    const float* table  = (const float*)d_in[3];
    const float* gmeans = (const float*)d_in[4];
    const float* gstds  = (const float*)d_in[5];
    const float* gmul   = (const float*)d_in[6];
    const float* gbias  = (const float*)d_in[7];
    const float* w1     = (const float*)d_in[8];
    const float* b1     = (const float*)d_in[9];
    const float* w2     = (const float*)d_in[10];
    const float* b2     = (const float*)d_in[11];
    const float* wq     = (const float*)d_in[12];
    const float* bq     = (const float*)d_in[13];
    const float* wk     = (const float*)d_in[14];
    const float* bk     = (const float*)d_in[15];
    const float* wv     = (const float*)d_in[16];
    const float* bv     = (const float*)d_in[17];
    const float* wo     = (const float*)d_in[18];
    const float* bo     = (const float*)d_in[19];
    const float* fw1    = (const float*)d_in[20];
    const float* fb1    = (const float*)d_in[21];
    const float* fw2    = (const float*)d_in[22];
    const float* fb2    = (const float*)d_in[23];
    const float* ln1g   = (const float*)d_in[24];
    const float* ln1b   = (const float*)d_in[25];
    const float* ln2g   = (const float*)d_in[26];
    const float* ln2b   = (const float*)d_in[27];

    const size_t MB = 1 << 20;
    char* cws = (char*)d_ws;
    bf16*  biasT   = (bf16*)(cws);             // 8MB [B,H,N,N]; reused as hiddenb
    bf16*  qkvb    = (bf16*)(cws + 8 * MB);    // 6MB: q | k [B,H,N,D], v^T [B,H,D,N]
    float* y       = (float*)(cws + 16 * MB);  // 4MB
    float* x1      = (float*)(cws + 20 * MB);  // 4MB
    bf16*  wbuf    = (bf16*)(cws + 24 * MB);   // 8MB (reused per weight)
    bf16*  nfeatb  = (bf16*)(cws + 32 * MB);   // 2MB
    bf16*  x1b     = (bf16*)(cws + 34 * MB);   // 2MB
    bf16*  attnob  = (bf16*)(cws + 36 * MB);   // 2MB
    float* bqkv    = (float*)(cws + 38 * MB);  // 12KB
    float* tw      = (float*)(cws + 38 * MB + 16384);
    bf16*  hiddenb = biasT;                    // [1024][4096] bf16

    tw_kernel<<<1, 512, 0, stream>>>(table, w1, tw);
    bpack_kernel<<<12, 256, 0, stream>>>(bq, bk, bv, bqkv);
    cvt_kernel<<<1024, 256, 0, stream>>>(nfeat, nfeatb);
    enc_kernel<<<1024, 256, 0, stream>>>(sp, rd, tw, gmeans, gstds, gmul, gbias,
                                         w1, b1, w2, b2, biasT);

    // QKV fused GEMM -> bf16 q/k/v^T
    wt_kernel<<<dim3(32, 32), 256, 0, stream>>>(wq, wbuf, 1024, 1024);
    wt_kernel<<<dim3(32, 32), 256, 0, stream>>>(wk, wbuf + 1048576, 1024, 1024);
    wt_kernel<<<dim3(32, 32), 256, 0, stream>>>(wv, wbuf + 2097152, 1024, 1024);
    gemm_bf16<<<dim3(24, 8), 256, 0, stream>>>(nfeatb, wbuf, bqkv, nullptr, qkvb,
                                               1024, 3072, 1024, 3);

    flash_kernel<<<256, 256, 0, stream>>>(qkvb, qkvb + 1048576, qkvb + 2097152,
                                          biasT, attnob);

    wt_kernel<<<dim3(32, 32), 256, 0, stream>>>(wo, wbuf, 1024, 1024);
    gemm_bf16<<<dim3(8, 8), 256, 0, stream>>>(attnob, wbuf, bo, nfeat, y,
                                              1024, 1024, 1024, 1);
    ln_kernel<<<1024, 256, 0, stream>>>(y, ln1g, ln1b, x1, x1b);

    wt_kernel<<<dim3(128, 32), 256, 0, stream>>>(fw1, wbuf, 1024, 4096);
    gemm_bf16<<<dim3(32, 8), 256, 0, stream>>>(x1b, wbuf, fb1, nullptr, hiddenb,
                                               1024, 4096, 1024, 2);

    wt_kernel<<<dim3(32, 128), 256, 0, stream>>>(fw2, wbuf, 4096, 1024);
    gemm_bf16<<<dim3(8, 8), 256, 0, stream>>>(hiddenb, wbuf, fb2, x1, y,
                                              1024, 1024, 4096, 1);

    ln_kernel<<<1024, 256, 0, stream>>>(y, ln2g, ln2b, (float*)d_out, nullptr);
}

// Round 4
// 229.961 us; speedup vs baseline: 3.4594x; 1.4618x over previous
//
#include <hip/hip_runtime.h>
#include <hip/hip_bf16.h>
#include <math.h>

// B=4, N=256, F=1024, H=16, K=128, HID=4096, TAB=32, D=64
typedef __hip_bfloat16 bf16;
typedef float f32x4 __attribute__((ext_vector_type(4)));
typedef short bf16x8 __attribute__((ext_vector_type(8)));

#define AS1 __attribute__((address_space(1)))
#define AS3 __attribute__((address_space(3)))

// ---------------- TW precompute: dist_table[32,128] @ mlp_w1[0:128,16] -> [32,16]
__global__ __launch_bounds__(512) void tw_kernel(const float* __restrict__ table,
                                                 const float* __restrict__ w1,
                                                 float* __restrict__ tw) {
    int t = threadIdx.x;
    int r = t >> 4, o = t & 15;
    float a = 0.f;
    for (int k = 0; k < 128; ++k) a += table[r * 128 + k] * w1[k * 16 + o];
    tw[t] = a;
}

// ---------------- pack QKV bias into one [3072] array
__global__ __launch_bounds__(256) void bpack_kernel(const float* __restrict__ bq,
                                                    const float* __restrict__ bk,
                                                    const float* __restrict__ bv,
                                                    float* __restrict__ bqkv) {
    int i = blockIdx.x * 256 + threadIdx.x;
    bqkv[i] = i < 1024 ? bq[i] : (i < 2048 ? bk[i - 1024] : bv[i - 2048]);
}

// ---------------- f32 -> bf16 elementwise
__global__ __launch_bounds__(256) void cvt_kernel(const float* __restrict__ x,
                                                  bf16* __restrict__ y) {
    int i = (blockIdx.x * 256 + threadIdx.x) * 4;
    float4 v = *reinterpret_cast<const float4*>(x + i);
    y[i + 0] = (bf16)v.x; y[i + 1] = (bf16)v.y;
    y[i + 2] = (bf16)v.z; y[i + 3] = (bf16)v.w;
}

// ---------------- transpose+convert: W[Kd][Nd] f32 -> WT[Nd][Kd] bf16
__global__ __launch_bounds__(256) void wt_kernel(const float* __restrict__ W,
                                                 bf16* __restrict__ WT, int Kd, int Nd) {
    __shared__ float tile[32][33];
    int t = threadIdx.x;
    int n0 = blockIdx.x * 32, k0 = blockIdx.y * 32;
    int tx = t & 31, ty = t >> 5;
    #pragma unroll
    for (int p = 0; p < 4; p++)
        tile[ty + p * 8][tx] = W[(k0 + ty + p * 8) * Nd + n0 + tx];
    __syncthreads();
    #pragma unroll
    for (int p = 0; p < 4; p++)
        WT[(n0 + ty + p * 8) * Kd + k0 + tx] = (bf16)tile[tx][ty + p * 8];
}

// ---------------- encoder: writes attn_bias TRANSPOSED as [B,H,N,N], bf16
__global__ __launch_bounds__(256) void enc_kernel(
    const int* __restrict__ sp, const float* __restrict__ rd,
    const float* __restrict__ tw,
    const float* __restrict__ means, const float* __restrict__ stds,
    const float* __restrict__ gmul, const float* __restrict__ gbias,
    const float* __restrict__ w1, const float* __restrict__ b1,
    const float* __restrict__ w2, const float* __restrict__ b2,
    bf16* __restrict__ biasT)
{
    __shared__ float w1s[128][16];
    __shared__ float w2s[16][16];
    __shared__ float b1s[16], b2s[16];
    __shared__ float meanS[128], istdS[128], coefS[128];
    int t = threadIdx.x;
    for (int i = t; i < 2048; i += 256) w1s[i >> 4][i & 15] = w1[2048 + i];
    w2s[t >> 4][t & 15] = w2[t];
    if (t < 16) { b1s[t] = b1[t]; b2s[t] = b2[t]; }
    if (t < 128) {
        float s = fabsf(stds[t]) + 0.01f;
        meanS[t] = means[t];
        istdS[t] = 1.f / s;
        coefS[t] = 1.f / (sqrtf(2.f * 3.14159f) * s);
    }
    __syncthreads();

    int p = blockIdx.x * 256 + t;
    int idx = sp[p];
    float xv = gmul[0] * rd[p] + gbias[0];

    float acc[16];
    #pragma unroll
    for (int o = 0; o < 16; o++) acc[o] = b1s[o] + tw[idx * 16 + o];

    for (int k = 0; k < 128; k++) {
        float d = (xv - meanS[k]) * istdS[k];
        float g = coefS[k] * __expf(-0.5f * d * d);
        #pragma unroll
        for (int o = 0; o < 16; o++) acc[o] += g * w1s[k][o];
    }
    float h[16];
    #pragma unroll
    for (int o = 0; o < 16; o++) {
        float a = acc[o];
        h[o] = 0.5f * a * (1.f + erff(a * 0.70710678118f));
    }
    float outv[16];
    #pragma unroll
    for (int o = 0; o < 16; o++) outv[o] = b2s[o];
    #pragma unroll
    for (int q = 0; q < 16; q++) {
        float hq = h[q];
        #pragma unroll
        for (int o = 0; o < 16; o++) outv[o] += hq * w2s[q][o];
    }
    int b = blockIdx.x >> 8, i = blockIdx.x & 255;
    #pragma unroll
    for (int hh = 0; hh < 16; hh++)
        biasT[(((b * 16 + hh) * 256 + i) << 8) + t] = (bf16)outv[hh];
}

// ---------------- bf16 MFMA GEMM (128x128 tile, BK=32, 4 waves 2x2),
// double-buffered LDS, optional split-K via blockIdx.z (f32 partials, no bias).
// epi: 0=+bias f32 ; 1=+bias+add f32 ; 2=relu(+bias) bf16 ;
// epi 3 = fused QKV epilogue bf16: q*8 [B,H,N,D] | k [B,H,N,D] | v^T [B,H,D,N]
__global__ __launch_bounds__(256, 2) void gemm_bf16(
    const bf16* __restrict__ A, const bf16* __restrict__ BT,
    const float* __restrict__ bias, const float* __restrict__ add,
    void* __restrict__ C, int M, int Nd, int Kd, int epi)
{
    __shared__ __align__(16) char smem[32768];   // 2 x (As 8KB | Bs 8KB)
    int t = threadIdx.x;
    int w = t >> 6, l = t & 63;
    int row0 = blockIdx.y * 128, col0 = blockIdx.x * 128;
    int wr = w >> 1, wc = w & 1;
    int nz = gridDim.z;
    int klen = Kd / nz;
    int kbeg = blockIdx.z * klen;

    f32x4 acc[4][4];
    #pragma unroll
    for (int i = 0; i < 4; i++)
        #pragma unroll
        for (int j = 0; j < 4; j++) acc[i][j] = (f32x4){0.f, 0.f, 0.f, 0.f};

    int sr = t & 127;
    int sc = t >> 7;
    const bf16* Asrc = A + (row0 + sr) * Kd + kbeg + sc * 8;
    const bf16* Bsrc = BT + (col0 + sr) * Kd + kbeg + sc * 8;
    int wbase = (t & 192) * 16;                  // w*1024

    int lr = l & 15, lc = l >> 4;
    int aoff = lc * 2048 + (wr * 64 + lr) * 16;
    int boff = 8192 + lc * 2048 + (wc * 64 + lr) * 16;

    // prologue: stage step 0 into buf 0
    #pragma unroll
    for (int p = 0; p < 2; p++) {
        __builtin_amdgcn_global_load_lds((const AS1 void*)(Asrc + p * 16),
                                         (AS3 void*)(smem + wbase + p * 4096), 16, 0, 0);
        __builtin_amdgcn_global_load_lds((const AS1 void*)(Bsrc + p * 16),
                                         (AS3 void*)(smem + 8192 + wbase + p * 4096), 16, 0, 0);
    }
    __syncthreads();

    int nsteps = klen >> 5;
    int cur = 0;
    for (int s = 0; s < nsteps; ++s) {
        int nxt = cur ^ 1;
        if (s + 1 < nsteps) {                    // prefetch next tile into buf^1
            const bf16* An = Asrc + (s + 1) * 32;
            const bf16* Bn = Bsrc + (s + 1) * 32;
            #pragma unroll
            for (int p = 0; p < 2; p++) {
                __builtin_amdgcn_global_load_lds((const AS1 void*)(An + p * 16),
                    (AS3 void*)(smem + nxt * 16384 + wbase + p * 4096), 16, 0, 0);
                __builtin_amdgcn_global_load_lds((const AS1 void*)(Bn + p * 16),
                    (AS3 void*)(smem + nxt * 16384 + 8192 + wbase + p * 4096), 16, 0, 0);
            }
        }
        const char* aRd = smem + cur * 16384 + aoff;
        const char* bRd = smem + cur * 16384 + boff;
        bf16x8 af[4], bfr[4];
        #pragma unroll
        for (int i = 0; i < 4; i++) af[i] = *(const bf16x8*)(aRd + i * 256);
        #pragma unroll
        for (int j = 0; j < 4; j++) bfr[j] = *(const bf16x8*)(bRd + j * 256);
        #pragma unroll
        for (int i = 0; i < 4; i++)
            #pragma unroll
            for (int j = 0; j < 4; j++)
                acc[i][j] = __builtin_amdgcn_mfma_f32_16x16x32_bf16(af[i], bfr[j], acc[i][j], 0, 0, 0);
        __syncthreads();                         // drains vmcnt -> next buf ready
        cur = nxt;
    }

    if (nz > 1) {                                // split-K: f32 partials, no bias
        float* P = (float*)C + (size_t)blockIdx.z * M * Nd;
        #pragma unroll
        for (int i = 0; i < 4; i++) {
            int rb = row0 + wr * 64 + i * 16 + lc * 4;
            #pragma unroll
            for (int j = 0; j < 4; j++) {
                int cc = col0 + wc * 64 + j * 16 + lr;
                f32x4 v = acc[i][j];
                #pragma unroll
                for (int q = 0; q < 4; q++) P[(rb + q) * Nd + cc] = v[q];
            }
        }
        return;
    }

    #pragma unroll
    for (int i = 0; i < 4; i++) {
        int rb = row0 + wr * 64 + i * 16 + lc * 4;
        #pragma unroll
        for (int j = 0; j < 4; j++) {
            int cc = col0 + wc * 64 + j * 16 + lr;
            float bsv = bias[cc];
            f32x4 v = acc[i][j];
            #pragma unroll
            for (int q = 0; q < 4; q++) {
                int r = rb + q;
                float x = v[q] + bsv;
                if (epi == 0) {
                    ((float*)C)[r * Nd + cc] = x;
                } else if (epi == 1) {
                    ((float*)C)[r * Nd + cc] = x + add[r * Nd + cc];
                } else if (epi == 2) {
                    ((bf16*)C)[r * Nd + cc] = (bf16)fmaxf(x, 0.f);
                } else {
                    bf16* Cb = (bf16*)C;
                    int sel = cc >> 10, ccc = cc & 1023;
                    int hh = ccc >> 6, dd = ccc & 63;
                    int bb = r >> 8, ii = r & 255;
                    if (sel == 0)
                        Cb[(((bb * 16 + hh) * 256 + ii) << 6) + dd] = (bf16)(x * 8.0f);
                    else if (sel == 1)
                        Cb[1048576 + (((bb * 16 + hh) * 256 + ii) << 6) + dd] = (bf16)x;
                    else
                        Cb[2097152 + ((((bb * 16 + hh) << 6) + dd) << 8) + ii] = (bf16)x;
                }
            }
        }
    }
}

// ---------------- split-K reduce: out = sum_s part[s] + bias + add  (M=Nd=1024)
__global__ __launch_bounds__(256) void redadd_kernel(
    const float* __restrict__ part, const float* __restrict__ bias,
    const float* __restrict__ add, float* __restrict__ out, int S)
{
    int i = (blockIdx.x * 256 + threadIdx.x) * 4;
    float4 a = *(const float4*)(part + i);
    for (int s = 1; s < S; s++) {
        float4 b = *(const float4*)(part + s * 1048576 + i);
        a.x += b.x; a.y += b.y; a.z += b.z; a.w += b.w;
    }
    float4 bs = *(const float4*)(bias + (i & 1023));
    float4 ad = *(const float4*)(add + i);
    a.x += bs.x + ad.x; a.y += bs.y + ad.y;
    a.z += bs.z + ad.z; a.w += bs.w + ad.w;
    *(float4*)(out + i) = a;
}

// ---------------- fused attention (unchanged from round 2)
__global__ __launch_bounds__(256) void flash_kernel(
    const bf16* __restrict__ Qb, const bf16* __restrict__ Kb,
    const bf16* __restrict__ VT, const bf16* __restrict__ biasT,
    bf16* __restrict__ out)
{
    __shared__ __align__(16) char pls[32768];
    int t = threadIdx.x;
    int w = t >> 6, l = t & 63;
    int lr = l & 15, hi = l >> 4;
    int bh = blockIdx.x >> 2, iq = blockIdx.x & 3;
    int b = bh >> 4, h = bh & 15;
    int i0 = iq * 64 + w * 16;

    const bf16* Qp = Qb + (bh * 256 + i0 + lr) * 64 + hi * 8;
    bf16x8 qf0 = *(const bf16x8*)(Qp);
    bf16x8 qf1 = *(const bf16x8*)(Qp + 32);

    f32x4 acc[16];
    #pragma unroll
    for (int f = 0; f < 16; f++) acc[f] = (f32x4){0.f, 0.f, 0.f, 0.f};

    const bf16* Kp = Kb + (bh * 256 + lr) * 64 + hi * 8;
    #pragma unroll
    for (int f = 0; f < 16; f++) {
        bf16x8 kf0 = *(const bf16x8*)(Kp + f * 1024);
        bf16x8 kf1 = *(const bf16x8*)(Kp + f * 1024 + 32);
        acc[f] = __builtin_amdgcn_mfma_f32_16x16x32_bf16(qf0, kf0, acc[f], 0, 0, 0);
        acc[f] = __builtin_amdgcn_mfma_f32_16x16x32_bf16(qf1, kf1, acc[f], 0, 0, 0);
    }

    const bf16* bp = biasT + (bh * 256 + i0 + hi * 4) * 256 + lr;
    #pragma unroll
    for (int f = 0; f < 16; f++)
        #pragma unroll
        for (int q = 0; q < 4; q++)
            acc[f][q] += __bfloat162float(bp[q * 256 + f * 16]);

    float inv[4];
    #pragma unroll
    for (int q = 0; q < 4; q++) {
        float m = acc[0][q];
        #pragma unroll
        for (int f = 1; f < 16; f++) m = fmaxf(m, acc[f][q]);
        #pragma unroll
        for (int msk = 1; msk < 16; msk <<= 1) m = fmaxf(m, __shfl_xor(m, msk));
        float s = 0.f;
        #pragma unroll
        for (int f = 0; f < 16; f++) {
            float e = __expf(acc[f][q] - m);
            acc[f][q] = e;
            s += e;
        }
        #pragma unroll
        for (int msk = 1; msk < 16; msk <<= 1) s += __shfl_xor(s, msk);
        inv[q] = 1.f / s;
    }

    char* Pw = pls + w * 8192;
    #pragma unroll
    for (int f = 0; f < 16; f++) {
        int j = f * 16 + lr;
        int c = j >> 3, jo = j & 7;
        #pragma unroll
        for (int q = 0; q < 4; q++)
            *(bf16*)(Pw + c * 256 + (hi * 4 + q) * 16 + jo * 2) = (bf16)(acc[f][q] * inv[q]);
    }
    __syncthreads();

    const char* Pr = pls + w * 8192 + hi * 256 + lr * 16;
    const bf16* Vp = VT + (bh * 64 + lr) * 256 + hi * 8;
    #pragma unroll
    for (int n = 0; n < 4; n++) {
        f32x4 o = (f32x4){0.f, 0.f, 0.f, 0.f};
        #pragma unroll
        for (int ks = 0; ks < 8; ks++) {
            bf16x8 pa = *(const bf16x8*)(Pr + ks * 1024);
            bf16x8 vb = *(const bf16x8*)(Vp + n * 4096 + ks * 32);
            o = __builtin_amdgcn_mfma_f32_16x16x32_bf16(pa, vb, o, 0, 0, 0);
        }
        #pragma unroll
        for (int q = 0; q < 4; q++)
            out[(b * 256 + i0 + hi * 4 + q) * 1024 + h * 64 + n * 16 + lr] = (bf16)o[q];
    }
}

// ---------------- row LayerNorm over F=1024; optional bf16 secondary output
__global__ __launch_bounds__(256) void ln_kernel(
    const float* __restrict__ x, const float* __restrict__ g,
    const float* __restrict__ bta, float* __restrict__ out, bf16* __restrict__ ob)
{
    int row = blockIdx.x;
    int t = threadIdx.x;
    const float* xr = x + row * 1024;
    float v[4];
    float sum = 0.f;
    #pragma unroll
    for (int i = 0; i < 4; i++) { v[i] = xr[t + i * 256]; sum += v[i]; }
    __shared__ float red[8];
    #pragma unroll
    for (int off = 32; off; off >>= 1) sum += __shfl_xor(sum, off);
    if ((t & 63) == 0) red[t >> 6] = sum;
    __syncthreads();
    float mean = (red[0] + red[1] + red[2] + red[3]) * (1.f / 1024.f);
    float vs = 0.f;
    #pragma unroll
    for (int i = 0; i < 4; i++) { float d = v[i] - mean; vs += d * d; }
    #pragma unroll
    for (int off = 32; off; off >>= 1) vs += __shfl_xor(vs, off);
    if ((t & 63) == 0) red[4 + (t >> 6)] = vs;
    __syncthreads();
    float var = (red[4] + red[5] + red[6] + red[7]) * (1.f / 1024.f);
    float invs = rsqrtf(var + 1e-5f);
    #pragma unroll
    for (int i = 0; i < 4; i++) {
        int c = t + i * 256;
        float o = (v[i] - mean) * invs * g[c] + bta[c];
        out[row * 1024 + c] = o;
        if (ob) ob[row * 1024 + c] = (bf16)o;
    }
}

extern "C" void kernel_launch(void* const* d_in, const int* in_sizes, int n_in,
                              void* d_out, int out_size, void* d_ws, size_t ws_size,
                              hipStream_t stream)
{
    const float* nfeat  = (const float*)d_in[0];
    const int*   sp     = (const int*)  d_in[1];
    const float* rd     = (const float*)d_in[2];
    const float* table  = (const float*)d_in[3];
    const float* gmeans = (const float*)d_in[4];
    const float* gstds  = (const float*)d_in[5];
    const float* gmul   = (const float*)d_in[6];
    const float* gbias  = (const float*)d_in[7];
    const float* w1     = (const float*)d_in[8];
    const float* b1     = (const float*)d_in[9];
    const float* w2     = (const float*)d_in[10];
    const float* b2     = (const float*)d_in[11];
    const float* wq     = (const float*)d_in[12];
    const float* bq     = (const float*)d_in[13];
    const float* wk     = (const float*)d_in[14];
    const float* bk     = (const float*)d_in[15];
    const float* wv     = (const float*)d_in[16];
    const float* bv     = (const float*)d_in[17];
    const float* wo     = (const float*)d_in[18];
    const float* bo     = (const float*)d_in[19];
    const float* fw1    = (const float*)d_in[20];
    const float* fb1    = (const float*)d_in[21];
    const float* fw2    = (const float*)d_in[22];
    const float* fb2    = (const float*)d_in[23];
    const float* ln1g   = (const float*)d_in[24];
    const float* ln1b   = (const float*)d_in[25];
    const float* ln2g   = (const float*)d_in[26];
    const float* ln2b   = (const float*)d_in[27];

    const size_t MB = 1 << 20;
    char* cws = (char*)d_ws;
    bf16*  biasT   = (bf16*)(cws);             // 8MB [B,H,N,N]; reused as hiddenb
    bf16*  qkvb    = (bf16*)(cws + 8 * MB);    // 6MB q|k [B,H,N,D], v^T [B,H,D,N]
    float* part    = (float*)(cws + 8 * MB);   // 8MB split-K partials (after flash)
    float* y       = (float*)(cws + 16 * MB);  // 4MB
    float* x1      = (float*)(cws + 20 * MB);  // 4MB
    bf16*  wbuf    = (bf16*)(cws + 24 * MB);   // 8MB (reused per weight)
    bf16*  nfeatb  = (bf16*)(cws + 32 * MB);   // 2MB
    bf16*  x1b     = (bf16*)(cws + 34 * MB);   // 2MB
    bf16*  attnob  = (bf16*)(cws + 36 * MB);   // 2MB
    float* bqkv    = (float*)(cws + 38 * MB);  // 12KB
    float* tw      = (float*)(cws + 38 * MB + 16384);
    bf16*  hiddenb = biasT;                    // [1024][4096] bf16

    tw_kernel<<<1, 512, 0, stream>>>(table, w1, tw);
    bpack_kernel<<<12, 256, 0, stream>>>(bq, bk, bv, bqkv);
    cvt_kernel<<<1024, 256, 0, stream>>>(nfeat, nfeatb);
    enc_kernel<<<1024, 256, 0, stream>>>(sp, rd, tw, gmeans, gstds, gmul, gbias,
                                         w1, b1, w2, b2, biasT);

    // QKV fused GEMM -> bf16 q/k/v^T
    wt_kernel<<<dim3(32, 32), 256, 0, stream>>>(wq, wbuf, 1024, 1024);
    wt_kernel<<<dim3(32, 32), 256, 0, stream>>>(wk, wbuf + 1048576, 1024, 1024);
    wt_kernel<<<dim3(32, 32), 256, 0, stream>>>(wv, wbuf + 2097152, 1024, 1024);
    gemm_bf16<<<dim3(24, 8), 256, 0, stream>>>(nfeatb, wbuf, bqkv, nullptr, qkvb,
                                               1024, 3072, 1024, 3);

    flash_kernel<<<256, 256, 0, stream>>>(qkvb, qkvb + 1048576, qkvb + 2097152,
                                          biasT, attnob);

    // Wo: split-K=2 -> partials -> reduce(+bo, +nfeat residual)
    wt_kernel<<<dim3(32, 32), 256, 0, stream>>>(wo, wbuf, 1024, 1024);
    gemm_bf16<<<dim3(8, 8, 2), 256, 0, stream>>>(attnob, wbuf, bo, nullptr, part,
                                                 1024, 1024, 1024, 0);
    redadd_kernel<<<1024, 256, 0, stream>>>(part, bo, nfeat, y, 2);
    ln_kernel<<<1024, 256, 0, stream>>>(y, ln1g, ln1b, x1, x1b);

    // FFN1: direct (grid fills machine)
    wt_kernel<<<dim3(128, 32), 256, 0, stream>>>(fw1, wbuf, 1024, 4096);
    gemm_bf16<<<dim3(32, 8), 256, 0, stream>>>(x1b, wbuf, fb1, nullptr, hiddenb,
                                               1024, 4096, 1024, 2);

    // FFN2: split-K=2 -> partials -> reduce(+fb2, +x1 residual)
    wt_kernel<<<dim3(32, 128), 256, 0, stream>>>(fw2, wbuf, 4096, 1024);
    gemm_bf16<<<dim3(8, 8, 2), 256, 0, stream>>>(hiddenb, wbuf, fb2, nullptr, part,
                                                 1024, 1024, 4096, 0);
    redadd_kernel<<<1024, 256, 0, stream>>>(part, fb2, x1, y, 2);

    ln_kernel<<<1024, 256, 0, stream>>>(y, ln2g, ln2b, (float*)d_out, nullptr);
}

// Round 5
// 205.929 us; speedup vs baseline: 3.8631x; 1.1167x over previous
//
#include <hip/hip_runtime.h>
#include <hip/hip_bf16.h>
#include <math.h>

// B=4, N=256, F=1024, H=16, K=128, HID=4096, TAB=32, D=64
typedef __hip_bfloat16 bf16;
typedef float f32x4 __attribute__((ext_vector_type(4)));
typedef short bf16x8 __attribute__((ext_vector_type(8)));

#define AS1 __attribute__((address_space(1)))
#define AS3 __attribute__((address_space(3)))

// ---------------- TW precompute: dist_table[32,128] @ mlp_w1[0:128,16] -> [32,16]
__global__ __launch_bounds__(512) void tw_kernel(const float* __restrict__ table,
                                                 const float* __restrict__ w1,
                                                 float* __restrict__ tw) {
    int t = threadIdx.x;
    int r = t >> 4, o = t & 15;
    float a = 0.f;
    for (int k = 0; k < 128; ++k) a += table[r * 128 + k] * w1[k * 16 + o];
    tw[t] = a;
}

// ---------------- pack QKV bias into one [3072] array
__global__ __launch_bounds__(256) void bpack_kernel(const float* __restrict__ bq,
                                                    const float* __restrict__ bk,
                                                    const float* __restrict__ bv,
                                                    float* __restrict__ bqkv) {
    int i = blockIdx.x * 256 + threadIdx.x;
    bqkv[i] = i < 1024 ? bq[i] : (i < 2048 ? bk[i - 1024] : bv[i - 2048]);
}

// ---------------- f32 -> bf16 elementwise
__global__ __launch_bounds__(256) void cvt_kernel(const float* __restrict__ x,
                                                  bf16* __restrict__ y) {
    int i = (blockIdx.x * 256 + threadIdx.x) * 4;
    float4 v = *reinterpret_cast<const float4*>(x + i);
    y[i + 0] = (bf16)v.x; y[i + 1] = (bf16)v.y;
    y[i + 2] = (bf16)v.z; y[i + 3] = (bf16)v.w;
}

// ---------------- transpose+convert: W[Kd][Nd] f32 -> WT[Nd][Kd] bf16
__global__ __launch_bounds__(256) void wt_kernel(const float* __restrict__ W,
                                                 bf16* __restrict__ WT, int Kd, int Nd) {
    __shared__ float tile[32][33];
    int t = threadIdx.x;
    int n0 = blockIdx.x * 32, k0 = blockIdx.y * 32;
    int tx = t & 31, ty = t >> 5;
    #pragma unroll
    for (int p = 0; p < 4; p++)
        tile[ty + p * 8][tx] = W[(k0 + ty + p * 8) * Nd + n0 + tx];
    __syncthreads();
    #pragma unroll
    for (int p = 0; p < 4; p++)
        WT[(n0 + ty + p * 8) * Kd + k0 + tx] = (bf16)tile[tx][ty + p * 8];
}

// ---------------- encoder: writes attn_bias TRANSPOSED as [B,H,N,N], bf16
__global__ __launch_bounds__(256) void enc_kernel(
    const int* __restrict__ sp, const float* __restrict__ rd,
    const float* __restrict__ tw,
    const float* __restrict__ means, const float* __restrict__ stds,
    const float* __restrict__ gmul, const float* __restrict__ gbias,
    const float* __restrict__ w1, const float* __restrict__ b1,
    const float* __restrict__ w2, const float* __restrict__ b2,
    bf16* __restrict__ biasT)
{
    __shared__ float w1s[128][16];
    __shared__ float w2s[16][16];
    __shared__ float b1s[16], b2s[16];
    __shared__ float meanS[128], istdS[128], coefS[128];
    int t = threadIdx.x;
    for (int i = t; i < 2048; i += 256) w1s[i >> 4][i & 15] = w1[2048 + i];
    w2s[t >> 4][t & 15] = w2[t];
    if (t < 16) { b1s[t] = b1[t]; b2s[t] = b2[t]; }
    if (t < 128) {
        float s = fabsf(stds[t]) + 0.01f;
        meanS[t] = means[t];
        istdS[t] = 1.f / s;
        coefS[t] = 1.f / (sqrtf(2.f * 3.14159f) * s);
    }
    __syncthreads();

    int p = blockIdx.x * 256 + t;
    int idx = sp[p];
    float xv = gmul[0] * rd[p] + gbias[0];

    float acc[16];
    #pragma unroll
    for (int o = 0; o < 16; o++) acc[o] = b1s[o] + tw[idx * 16 + o];

    for (int k = 0; k < 128; k++) {
        float d = (xv - meanS[k]) * istdS[k];
        float g = coefS[k] * __expf(-0.5f * d * d);
        #pragma unroll
        for (int o = 0; o < 16; o++) acc[o] += g * w1s[k][o];
    }
    float h[16];
    #pragma unroll
    for (int o = 0; o < 16; o++) {
        float a = acc[o];
        h[o] = 0.5f * a * (1.f + erff(a * 0.70710678118f));
    }
    float outv[16];
    #pragma unroll
    for (int o = 0; o < 16; o++) outv[o] = b2s[o];
    #pragma unroll
    for (int q = 0; q < 16; q++) {
        float hq = h[q];
        #pragma unroll
        for (int o = 0; o < 16; o++) outv[o] += hq * w2s[q][o];
    }
    int b = blockIdx.x >> 8, i = blockIdx.x & 255;
    #pragma unroll
    for (int hh = 0; hh < 16; hh++)
        biasT[(((b * 16 + hh) * 256 + i) << 8) + t] = (bf16)outv[hh];
}

// ---------------- bf16 MFMA GEMM, 64x64 tile, BK=32, 4 waves (2x2, each 32x32),
// double-buffered LDS (16KB), optional split-K via blockIdx.z (f32 partials).
// epi: 0=+bias f32 ; 1=+bias+add f32 ; 2=relu(+bias) bf16 ;
// epi 3 = fused QKV epilogue bf16: q*8 [B,H,N,D] | k [B,H,N,D] | v^T [B,H,D,N]
__global__ __launch_bounds__(256, 2) void gemm_bf16(
    const bf16* __restrict__ A, const bf16* __restrict__ BT,
    const float* __restrict__ bias, const float* __restrict__ add,
    void* __restrict__ C, int M, int Nd, int Kd, int epi)
{
    __shared__ __align__(16) char smem[16384];   // 2 bufs x (As 4KB | Bs 4KB)
    int t = threadIdx.x;
    int w = t >> 6, l = t & 63;
    int wr = w >> 1, wc = w & 1;
    int lr = l & 15, hi = l >> 4;
    int row0 = blockIdx.y * 64, col0 = blockIdx.x * 64;
    int nz = gridDim.z;
    int klen = Kd / nz;
    int kbeg = blockIdx.z * klen;

    f32x4 acc[2][2];
    #pragma unroll
    for (int i = 0; i < 2; i++)
        #pragma unroll
        for (int j = 0; j < 2; j++) acc[i][j] = (f32x4){0.f, 0.f, 0.f, 0.f};

    // staging: thread t covers row (t&63), k-octet (t>>6); LDS dest = t*16 (linear)
    const bf16* Asrc = A + (row0 + (t & 63)) * Kd + kbeg + (t >> 6) * 8;
    const bf16* Bsrc = BT + (col0 + (t & 63)) * Kd + kbeg + (t >> 6) * 8;
    int wbase = (t & 192) * 16;                  // wave-uniform w*1024

    int aoff0 = hi * 1024 + (wr * 32 + lr) * 16;         // mi=0
    int boff0 = 4096 + hi * 1024 + (wc * 32 + lr) * 16;  // ni=0

    // prologue: stage step 0 into buf 0
    __builtin_amdgcn_global_load_lds((const AS1 void*)Asrc,
                                     (AS3 void*)(smem + wbase), 16, 0, 0);
    __builtin_amdgcn_global_load_lds((const AS1 void*)Bsrc,
                                     (AS3 void*)(smem + 4096 + wbase), 16, 0, 0);
    __syncthreads();

    int nsteps = klen >> 5;
    int cur = 0;
    for (int s = 0; s < nsteps; ++s) {
        int nxt = cur ^ 1;
        if (s + 1 < nsteps) {                    // prefetch next tile into buf^1
            __builtin_amdgcn_global_load_lds((const AS1 void*)(Asrc + (s + 1) * 32),
                (AS3 void*)(smem + nxt * 8192 + wbase), 16, 0, 0);
            __builtin_amdgcn_global_load_lds((const AS1 void*)(Bsrc + (s + 1) * 32),
                (AS3 void*)(smem + nxt * 8192 + 4096 + wbase), 16, 0, 0);
        }
        const char* base = smem + cur * 8192;
        bf16x8 af[2], bfr[2];
        af[0] = *(const bf16x8*)(base + aoff0);
        af[1] = *(const bf16x8*)(base + aoff0 + 256);
        bfr[0] = *(const bf16x8*)(base + boff0);
        bfr[1] = *(const bf16x8*)(base + boff0 + 256);
        #pragma unroll
        for (int i = 0; i < 2; i++)
            #pragma unroll
            for (int j = 0; j < 2; j++)
                acc[i][j] = __builtin_amdgcn_mfma_f32_16x16x32_bf16(af[i], bfr[j], acc[i][j], 0, 0, 0);
        __syncthreads();                         // drains vmcnt -> next buf ready
        cur = nxt;
    }

    if (nz > 1) {                                // split-K: f32 partials, no bias
        float* P = (float*)C + (size_t)blockIdx.z * M * Nd;
        #pragma unroll
        for (int i = 0; i < 2; i++) {
            int rb = row0 + wr * 32 + i * 16 + hi * 4;
            #pragma unroll
            for (int j = 0; j < 2; j++) {
                int cc = col0 + wc * 32 + j * 16 + lr;
                f32x4 v = acc[i][j];
                #pragma unroll
                for (int q = 0; q < 4; q++) P[(rb + q) * Nd + cc] = v[q];
            }
        }
        return;
    }

    #pragma unroll
    for (int i = 0; i < 2; i++) {
        int rb = row0 + wr * 32 + i * 16 + hi * 4;
        #pragma unroll
        for (int j = 0; j < 2; j++) {
            int cc = col0 + wc * 32 + j * 16 + lr;
            float bsv = bias[cc];
            f32x4 v = acc[i][j];
            #pragma unroll
            for (int q = 0; q < 4; q++) {
                int r = rb + q;
                float x = v[q] + bsv;
                if (epi == 0) {
                    ((float*)C)[r * Nd + cc] = x;
                } else if (epi == 1) {
                    ((float*)C)[r * Nd + cc] = x + add[r * Nd + cc];
                } else if (epi == 2) {
                    ((bf16*)C)[r * Nd + cc] = (bf16)fmaxf(x, 0.f);
                } else {
                    bf16* Cb = (bf16*)C;
                    int sel = cc >> 10, ccc = cc & 1023;
                    int hh = ccc >> 6, dd = ccc & 63;
                    int bb = r >> 8, ii = r & 255;
                    if (sel == 0)
                        Cb[(((bb * 16 + hh) * 256 + ii) << 6) + dd] = (bf16)(x * 8.0f);
                    else if (sel == 1)
                        Cb[1048576 + (((bb * 16 + hh) * 256 + ii) << 6) + dd] = (bf16)x;
                    else
                        Cb[2097152 + ((((bb * 16 + hh) << 6) + dd) << 8) + ii] = (bf16)x;
                }
            }
        }
    }
}

// ---------------- split-K reduce: out = sum_s part[s] + bias + add  (M=Nd=1024)
__global__ __launch_bounds__(256) void redadd_kernel(
    const float* __restrict__ part, const float* __restrict__ bias,
    const float* __restrict__ add, float* __restrict__ out, int S)
{
    int i = (blockIdx.x * 256 + threadIdx.x) * 4;
    float4 a = *(const float4*)(part + i);
    for (int s = 1; s < S; s++) {
        float4 b = *(const float4*)(part + s * 1048576 + i);
        a.x += b.x; a.y += b.y; a.z += b.z; a.w += b.w;
    }
    float4 bs = *(const float4*)(bias + (i & 1023));
    float4 ad = *(const float4*)(add + i);
    a.x += bs.x + ad.x; a.y += bs.y + ad.y;
    a.z += bs.z + ad.z; a.w += bs.w + ad.w;
    *(float4*)(out + i) = a;
}

// ---------------- fused attention (unchanged)
__global__ __launch_bounds__(256) void flash_kernel(
    const bf16* __restrict__ Qb, const bf16* __restrict__ Kb,
    const bf16* __restrict__ VT, const bf16* __restrict__ biasT,
    bf16* __restrict__ out)
{
    __shared__ __align__(16) char pls[32768];
    int t = threadIdx.x;
    int w = t >> 6, l = t & 63;
    int lr = l & 15, hi = l >> 4;
    int bh = blockIdx.x >> 2, iq = blockIdx.x & 3;
    int b = bh >> 4, h = bh & 15;
    int i0 = iq * 64 + w * 16;

    const bf16* Qp = Qb + (bh * 256 + i0 + lr) * 64 + hi * 8;
    bf16x8 qf0 = *(const bf16x8*)(Qp);
    bf16x8 qf1 = *(const bf16x8*)(Qp + 32);

    f32x4 acc[16];
    #pragma unroll
    for (int f = 0; f < 16; f++) acc[f] = (f32x4){0.f, 0.f, 0.f, 0.f};

    const bf16* Kp = Kb + (bh * 256 + lr) * 64 + hi * 8;
    #pragma unroll
    for (int f = 0; f < 16; f++) {
        bf16x8 kf0 = *(const bf16x8*)(Kp + f * 1024);
        bf16x8 kf1 = *(const bf16x8*)(Kp + f * 1024 + 32);
        acc[f] = __builtin_amdgcn_mfma_f32_16x16x32_bf16(qf0, kf0, acc[f], 0, 0, 0);
        acc[f] = __builtin_amdgcn_mfma_f32_16x16x32_bf16(qf1, kf1, acc[f], 0, 0, 0);
    }

    const bf16* bp = biasT + (bh * 256 + i0 + hi * 4) * 256 + lr;
    #pragma unroll
    for (int f = 0; f < 16; f++)
        #pragma unroll
        for (int q = 0; q < 4; q++)
            acc[f][q] += __bfloat162float(bp[q * 256 + f * 16]);

    float inv[4];
    #pragma unroll
    for (int q = 0; q < 4; q++) {
        float m = acc[0][q];
        #pragma unroll
        for (int f = 1; f < 16; f++) m = fmaxf(m, acc[f][q]);
        #pragma unroll
        for (int msk = 1; msk < 16; msk <<= 1) m = fmaxf(m, __shfl_xor(m, msk));
        float s = 0.f;
        #pragma unroll
        for (int f = 0; f < 16; f++) {
            float e = __expf(acc[f][q] - m);
            acc[f][q] = e;
            s += e;
        }
        #pragma unroll
        for (int msk = 1; msk < 16; msk <<= 1) s += __shfl_xor(s, msk);
        inv[q] = 1.f / s;
    }

    char* Pw = pls + w * 8192;
    #pragma unroll
    for (int f = 0; f < 16; f++) {
        int j = f * 16 + lr;
        int c = j >> 3, jo = j & 7;
        #pragma unroll
        for (int q = 0; q < 4; q++)
            *(bf16*)(Pw + c * 256 + (hi * 4 + q) * 16 + jo * 2) = (bf16)(acc[f][q] * inv[q]);
    }
    __syncthreads();

    const char* Pr = pls + w * 8192 + hi * 256 + lr * 16;
    const bf16* Vp = VT + (bh * 64 + lr) * 256 + hi * 8;
    #pragma unroll
    for (int n = 0; n < 4; n++) {
        f32x4 o = (f32x4){0.f, 0.f, 0.f, 0.f};
        #pragma unroll
        for (int ks = 0; ks < 8; ks++) {
            bf16x8 pa = *(const bf16x8*)(Pr + ks * 1024);
            bf16x8 vb = *(const bf16x8*)(Vp + n * 4096 + ks * 32);
            o = __builtin_amdgcn_mfma_f32_16x16x32_bf16(pa, vb, o, 0, 0, 0);
        }
        #pragma unroll
        for (int q = 0; q < 4; q++)
            out[(b * 256 + i0 + hi * 4 + q) * 1024 + h * 64 + n * 16 + lr] = (bf16)o[q];
    }
}

// ---------------- row LayerNorm over F=1024; optional bf16 secondary output
__global__ __launch_bounds__(256) void ln_kernel(
    const float* __restrict__ x, const float* __restrict__ g,
    const float* __restrict__ bta, float* __restrict__ out, bf16* __restrict__ ob)
{
    int row = blockIdx.x;
    int t = threadIdx.x;
    const float* xr = x + row * 1024;
    float v[4];
    float sum = 0.f;
    #pragma unroll
    for (int i = 0; i < 4; i++) { v[i] = xr[t + i * 256]; sum += v[i]; }
    __shared__ float red[8];
    #pragma unroll
    for (int off = 32; off; off >>= 1) sum += __shfl_xor(sum, off);
    if ((t & 63) == 0) red[t >> 6] = sum;
    __syncthreads();
    float mean = (red[0] + red[1] + red[2] + red[3]) * (1.f / 1024.f);
    float vs = 0.f;
    #pragma unroll
    for (int i = 0; i < 4; i++) { float d = v[i] - mean; vs += d * d; }
    #pragma unroll
    for (int off = 32; off; off >>= 1) vs += __shfl_xor(vs, off);
    if ((t & 63) == 0) red[4 + (t >> 6)] = vs;
    __syncthreads();
    float var = (red[4] + red[5] + red[6] + red[7]) * (1.f / 1024.f);
    float invs = rsqrtf(var + 1e-5f);
    #pragma unroll
    for (int i = 0; i < 4; i++) {
        int c = t + i * 256;
        float o = (v[i] - mean) * invs * g[c] + bta[c];
        out[row * 1024 + c] = o;
        if (ob) ob[row * 1024 + c] = (bf16)o;
    }
}

extern "C" void kernel_launch(void* const* d_in, const int* in_sizes, int n_in,
                              void* d_out, int out_size, void* d_ws, size_t ws_size,
                              hipStream_t stream)
{
    const float* nfeat  = (const float*)d_in[0];
    const int*   sp     = (const int*)  d_in[1];
    const float* rd     = (const float*)d_in[2];
    const float* table  = (const float*)d_in[3];
    const float* gmeans = (const float*)d_in[4];
    const float* gstds  = (const float*)d_in[5];
    const float* gmul   = (const float*)d_in[6];
    const float* gbias  = (const float*)d_in[7];
    const float* w1     = (const float*)d_in[8];
    const float* b1     = (const float*)d_in[9];
    const float* w2     = (const float*)d_in[10];
    const float* b2     = (const float*)d_in[11];
    const float* wq     = (const float*)d_in[12];
    const float* bq     = (const float*)d_in[13];
    const float* wk     = (const float*)d_in[14];
    const float* bk     = (const float*)d_in[15];
    const float* wv     = (const float*)d_in[16];
    const float* bv     = (const float*)d_in[17];
    const float* wo     = (const float*)d_in[18];
    const float* bo     = (const float*)d_in[19];
    const float* fw1    = (const float*)d_in[20];
    const float* fb1    = (const float*)d_in[21];
    const float* fw2    = (const float*)d_in[22];
    const float* fb2    = (const float*)d_in[23];
    const float* ln1g   = (const float*)d_in[24];
    const float* ln1b   = (const float*)d_in[25];
    const float* ln2g   = (const float*)d_in[26];
    const float* ln2b   = (const float*)d_in[27];

    const size_t MB = 1 << 20;
    char* cws = (char*)d_ws;
    bf16*  biasT   = (bf16*)(cws);             // 8MB [B,H,N,N]; reused as hiddenb
    bf16*  qkvb    = (bf16*)(cws + 8 * MB);    // 6MB q|k [B,H,N,D], v^T [B,H,D,N]
    float* bqkv    = (float*)(cws + 14 * MB);  // 12KB
    float* tw      = (float*)(cws + 14 * MB + 16384);
    float* part    = (float*)(cws + 16 * MB);  // 16MB split-K partials (S<=4)
    float* y       = (float*)(cws + 32 * MB);  // 4MB
    float* x1      = (float*)(cws + 36 * MB);  // 4MB
    bf16*  wbuf    = (bf16*)(cws + 40 * MB);   // 8MB (reused per weight)
    bf16*  nfeatb  = (bf16*)(cws + 48 * MB);   // 2MB
    bf16*  x1b     = (bf16*)(cws + 50 * MB);   // 2MB
    bf16*  attnob  = (bf16*)(cws + 52 * MB);   // 2MB
    bf16*  hiddenb = biasT;                    // [1024][4096] bf16

    tw_kernel<<<1, 512, 0, stream>>>(table, w1, tw);
    bpack_kernel<<<12, 256, 0, stream>>>(bq, bk, bv, bqkv);
    cvt_kernel<<<1024, 256, 0, stream>>>(nfeat, nfeatb);
    enc_kernel<<<1024, 256, 0, stream>>>(sp, rd, tw, gmeans, gstds, gmul, gbias,
                                         w1, b1, w2, b2, biasT);

    // QKV fused GEMM -> bf16 q/k/v^T
    wt_kernel<<<dim3(32, 32), 256, 0, stream>>>(wq, wbuf, 1024, 1024);
    wt_kernel<<<dim3(32, 32), 256, 0, stream>>>(wk, wbuf + 1048576, 1024, 1024);
    wt_kernel<<<dim3(32, 32), 256, 0, stream>>>(wv, wbuf + 2097152, 1024, 1024);
    gemm_bf16<<<dim3(48, 16), 256, 0, stream>>>(nfeatb, wbuf, bqkv, nullptr, qkvb,
                                                1024, 3072, 1024, 3);

    flash_kernel<<<256, 256, 0, stream>>>(qkvb, qkvb + 1048576, qkvb + 2097152,
                                          biasT, attnob);

    // Wo: split-K=2 -> partials -> reduce(+bo, +nfeat residual)
    wt_kernel<<<dim3(32, 32), 256, 0, stream>>>(wo, wbuf, 1024, 1024);
    gemm_bf16<<<dim3(16, 16, 2), 256, 0, stream>>>(attnob, wbuf, bo, nullptr, part,
                                                   1024, 1024, 1024, 0);
    redadd_kernel<<<1024, 256, 0, stream>>>(part, bo, nfeat, y, 2);
    ln_kernel<<<1024, 256, 0, stream>>>(y, ln1g, ln1b, x1, x1b);

    // FFN1: direct (1024 blocks)
    wt_kernel<<<dim3(128, 32), 256, 0, stream>>>(fw1, wbuf, 1024, 4096);
    gemm_bf16<<<dim3(64, 16), 256, 0, stream>>>(x1b, wbuf, fb1, nullptr, hiddenb,
                                                1024, 4096, 1024, 2);

    // FFN2: split-K=4 -> partials -> reduce(+fb2, +x1 residual)
    wt_kernel<<<dim3(32, 128), 256, 0, stream>>>(fw2, wbuf, 4096, 1024);
    gemm_bf16<<<dim3(16, 16, 4), 256, 0, stream>>>(hiddenb, wbuf, fb2, nullptr, part,
                                                   1024, 1024, 4096, 0);
    redadd_kernel<<<1024, 256, 0, stream>>>(part, fb2, x1, y, 4);

    ln_kernel<<<1024, 256, 0, stream>>>(y, ln2g, ln2b, (float*)d_out, nullptr);
}

// Round 6
// 194.829 us; speedup vs baseline: 4.0832x; 1.0570x over previous
//
#include <hip/hip_runtime.h>
#include <hip/hip_bf16.h>
#include <math.h>

// B=4, N=256, F=1024, H=16, K=128, HID=4096, TAB=32, D=64
typedef __hip_bfloat16 bf16;
typedef float f32x4 __attribute__((ext_vector_type(4)));
typedef short bf16x8 __attribute__((ext_vector_type(8)));

#define AS1 __attribute__((address_space(1)))
#define AS3 __attribute__((address_space(3)))

// ---------------- setup: cvt nfeat->bf16 | pack qkv bias | TW table
__global__ __launch_bounds__(256) void setup_kernel(
    const float* __restrict__ nfeat, bf16* __restrict__ nfeatb,
    const float* __restrict__ bq, const float* __restrict__ bk,
    const float* __restrict__ bv, float* __restrict__ bqkv,
    const float* __restrict__ table, const float* __restrict__ w1,
    float* __restrict__ tw)
{
    int bid = blockIdx.x, t = threadIdx.x;
    if (bid < 1024) {
        int i = (bid * 256 + t) * 4;
        float4 v = *reinterpret_cast<const float4*>(nfeat + i);
        nfeatb[i + 0] = (bf16)v.x; nfeatb[i + 1] = (bf16)v.y;
        nfeatb[i + 2] = (bf16)v.z; nfeatb[i + 3] = (bf16)v.w;
    } else if (bid < 1036) {
        int i = (bid - 1024) * 256 + t;
        bqkv[i] = i < 1024 ? bq[i] : (i < 2048 ? bk[i - 1024] : bv[i - 2048]);
    } else {
        #pragma unroll
        for (int e = t; e < 512; e += 256) {
            int r = e >> 4, o = e & 15;
            float a = 0.f;
            for (int k = 0; k < 128; ++k) a += table[r * 128 + k] * w1[k * 16 + o];
            tw[e] = a;
        }
    }
}

// ---------------- all weight transposes (f32 [Kd][Nd] -> bf16 [Nd][Kd]) in one grid
__global__ __launch_bounds__(256) void wt_all_kernel(
    const float* __restrict__ wq, const float* __restrict__ wk,
    const float* __restrict__ wv, const float* __restrict__ wo,
    const float* __restrict__ fw1, const float* __restrict__ fw2,
    bf16* __restrict__ qkvT, bf16* __restrict__ woT,
    bf16* __restrict__ fw1T, bf16* __restrict__ fw2T)
{
    __shared__ float tile[32][33];
    int bid = blockIdx.x, t = threadIdx.x;
    const float* W; bf16* WT; int Kd, Nd, local;
    if (bid < 3072)      { int ws = bid >> 10; local = bid & 1023;
                           W = ws == 0 ? wq : ws == 1 ? wk : wv;
                           WT = qkvT + ws * 1048576; Kd = 1024; Nd = 1024; }
    else if (bid < 4096) { local = bid - 3072; W = wo;  WT = woT;  Kd = 1024; Nd = 1024; }
    else if (bid < 8192) { local = bid - 4096; W = fw1; WT = fw1T; Kd = 1024; Nd = 4096; }
    else                 { local = bid - 8192; W = fw2; WT = fw2T; Kd = 4096; Nd = 1024; }
    int ntn = Nd >> 5;
    int n0 = (local % ntn) * 32, k0 = (local / ntn) * 32;
    int tx = t & 31, ty = t >> 5;
    #pragma unroll
    for (int p = 0; p < 4; p++)
        tile[ty + p * 8][tx] = W[(k0 + ty + p * 8) * Nd + n0 + tx];
    __syncthreads();
    #pragma unroll
    for (int p = 0; p < 4; p++)
        WT[(n0 + ty + p * 8) * Kd + k0 + tx] = (bf16)tile[tx][ty + p * 8];
}

// ---------------- encoder: writes attn_bias TRANSPOSED as [B,H,N,N], bf16
__global__ __launch_bounds__(256) void enc_kernel(
    const int* __restrict__ sp, const float* __restrict__ rd,
    const float* __restrict__ tw,
    const float* __restrict__ means, const float* __restrict__ stds,
    const float* __restrict__ gmul, const float* __restrict__ gbias,
    const float* __restrict__ w1, const float* __restrict__ b1,
    const float* __restrict__ w2, const float* __restrict__ b2,
    bf16* __restrict__ biasT)
{
    __shared__ float w1s[128][16];
    __shared__ float w2s[16][16];
    __shared__ float b1s[16], b2s[16];
    __shared__ float meanS[128], istdS[128], coefS[128];
    int t = threadIdx.x;
    for (int i = t; i < 2048; i += 256) w1s[i >> 4][i & 15] = w1[2048 + i];
    w2s[t >> 4][t & 15] = w2[t];
    if (t < 16) { b1s[t] = b1[t]; b2s[t] = b2[t]; }
    if (t < 128) {
        float s = fabsf(stds[t]) + 0.01f;
        meanS[t] = means[t];
        istdS[t] = 1.f / s;
        coefS[t] = 1.f / (sqrtf(2.f * 3.14159f) * s);
    }
    __syncthreads();

    int p = blockIdx.x * 256 + t;
    int idx = sp[p];
    float xv = gmul[0] * rd[p] + gbias[0];

    float acc[16];
    #pragma unroll
    for (int o = 0; o < 16; o++) acc[o] = b1s[o] + tw[idx * 16 + o];

    for (int k = 0; k < 128; k++) {
        float d = (xv - meanS[k]) * istdS[k];
        float g = coefS[k] * __expf(-0.5f * d * d);
        #pragma unroll
        for (int o = 0; o < 16; o++) acc[o] += g * w1s[k][o];
    }
    float h[16];
    #pragma unroll
    for (int o = 0; o < 16; o++) {
        float a = acc[o];
        h[o] = 0.5f * a * (1.f + erff(a * 0.70710678118f));
    }
    float outv[16];
    #pragma unroll
    for (int o = 0; o < 16; o++) outv[o] = b2s[o];
    #pragma unroll
    for (int q = 0; q < 16; q++) {
        float hq = h[q];
        #pragma unroll
        for (int o = 0; o < 16; o++) outv[o] += hq * w2s[q][o];
    }
    int b = blockIdx.x >> 8, i = blockIdx.x & 255;
    #pragma unroll
    for (int hh = 0; hh < 16; hh++)
        biasT[(((b * 16 + hh) * 256 + i) << 8) + t] = (bf16)outv[hh];
}

// ---------------- bf16 MFMA GEMM, 64x64 tile, BK=64, 4 waves (2x2, each 32x32),
// double-buffered LDS (32KB), optional split-K via blockIdx.z (f32 partials).
// 8 MFMA + 8 ds_read_b128 per wave per barrier (2x the BK=32 version).
// epi: 0=+bias f32 ; 1=+bias+add f32 ; 2=relu(+bias) bf16 ;
// epi 3 = fused QKV epilogue bf16: q*8 [B,H,N,D] | k [B,H,N,D] | v^T [B,H,D,N]
__global__ __launch_bounds__(256, 4) void gemm_bf16(
    const bf16* __restrict__ A, const bf16* __restrict__ BT,
    const float* __restrict__ bias, const float* __restrict__ add,
    void* __restrict__ C, int M, int Nd, int Kd, int epi)
{
    __shared__ __align__(16) char smem[32768];   // 2 bufs x (As 8KB | Bs 8KB)
    int t = threadIdx.x;
    int w = t >> 6, l = t & 63;
    int wr = w >> 1, wc = w & 1;
    int lr = l & 15, hi = l >> 4;
    int row0 = blockIdx.y * 64, col0 = blockIdx.x * 64;
    int nz = gridDim.z;
    int klen = Kd / nz;
    int kbeg = blockIdx.z * klen;

    f32x4 acc[2][2];
    #pragma unroll
    for (int i = 0; i < 2; i++)
        #pragma unroll
        for (int j = 0; j < 2; j++) acc[i][j] = (f32x4){0.f, 0.f, 0.f, 0.f};

    // staging: thread t = oct(t>>6)*64 + row(t&63); k-octet c = p*4+oct at LDS c*1024+row*16
    const bf16* Asrc = A + (row0 + (t & 63)) * Kd + kbeg + (t >> 6) * 8;
    const bf16* Bsrc = BT + (col0 + (t & 63)) * Kd + kbeg + (t >> 6) * 8;
    int wbase = (t & 192) * 16;                  // wave-uniform w*1024

    // prologue: stage step 0 into buf 0 (A: issues p=0,1 ; B same)
    #pragma unroll
    for (int p = 0; p < 2; p++) {
        __builtin_amdgcn_global_load_lds((const AS1 void*)(Asrc + p * 32),
                                         (AS3 void*)(smem + p * 4096 + wbase), 16, 0, 0);
        __builtin_amdgcn_global_load_lds((const AS1 void*)(Bsrc + p * 32),
                                         (AS3 void*)(smem + 8192 + p * 4096 + wbase), 16, 0, 0);
    }
    __syncthreads();

    int nsteps = klen >> 6;
    int cur = 0;
    for (int s = 0; s < nsteps; ++s) {
        int nxt = cur ^ 1;
        if (s + 1 < nsteps) {                    // prefetch next K-tile into buf^1
            const bf16* An = Asrc + (s + 1) * 64;
            const bf16* Bn = Bsrc + (s + 1) * 64;
            #pragma unroll
            for (int p = 0; p < 2; p++) {
                __builtin_amdgcn_global_load_lds((const AS1 void*)(An + p * 32),
                    (AS3 void*)(smem + nxt * 16384 + p * 4096 + wbase), 16, 0, 0);
                __builtin_amdgcn_global_load_lds((const AS1 void*)(Bn + p * 32),
                    (AS3 void*)(smem + nxt * 16384 + 8192 + p * 4096 + wbase), 16, 0, 0);
            }
        }
        const char* base = smem + cur * 16384;
        bf16x8 af[2][2], bfr[2][2];
        #pragma unroll
        for (int kk = 0; kk < 2; kk++) {
            #pragma unroll
            for (int mi = 0; mi < 2; mi++)
                af[kk][mi] = *(const bf16x8*)(base + kk * 4096 + hi * 1024 +
                                              (wr * 32 + mi * 16 + lr) * 16);
            #pragma unroll
            for (int nj = 0; nj < 2; nj++)
                bfr[kk][nj] = *(const bf16x8*)(base + 8192 + kk * 4096 + hi * 1024 +
                                               (wc * 32 + nj * 16 + lr) * 16);
        }
        #pragma unroll
        for (int kk = 0; kk < 2; kk++)
            #pragma unroll
            for (int mi = 0; mi < 2; mi++)
                #pragma unroll
                for (int nj = 0; nj < 2; nj++)
                    acc[mi][nj] = __builtin_amdgcn_mfma_f32_16x16x32_bf16(
                        af[kk][mi], bfr[kk][nj], acc[mi][nj], 0, 0, 0);
        __syncthreads();
        cur = nxt;
    }

    if (nz > 1) {                                // split-K: f32 partials, no bias
        float* P = (float*)C + (size_t)blockIdx.z * M * Nd;
        #pragma unroll
        for (int i = 0; i < 2; i++) {
            int rb = row0 + wr * 32 + i * 16 + hi * 4;
            #pragma unroll
            for (int j = 0; j < 2; j++) {
                int cc = col0 + wc * 32 + j * 16 + lr;
                f32x4 v = acc[i][j];
                #pragma unroll
                for (int q = 0; q < 4; q++) P[(rb + q) * Nd + cc] = v[q];
            }
        }
        return;
    }

    #pragma unroll
    for (int i = 0; i < 2; i++) {
        int rb = row0 + wr * 32 + i * 16 + hi * 4;
        #pragma unroll
        for (int j = 0; j < 2; j++) {
            int cc = col0 + wc * 32 + j * 16 + lr;
            float bsv = bias[cc];
            f32x4 v = acc[i][j];
            #pragma unroll
            for (int q = 0; q < 4; q++) {
                int r = rb + q;
                float x = v[q] + bsv;
                if (epi == 0) {
                    ((float*)C)[r * Nd + cc] = x;
                } else if (epi == 1) {
                    ((float*)C)[r * Nd + cc] = x + add[r * Nd + cc];
                } else if (epi == 2) {
                    ((bf16*)C)[r * Nd + cc] = (bf16)fmaxf(x, 0.f);
                } else {
                    bf16* Cb = (bf16*)C;
                    int sel = cc >> 10, ccc = cc & 1023;
                    int hh = ccc >> 6, dd = ccc & 63;
                    int bb = r >> 8, ii = r & 255;
                    if (sel == 0)
                        Cb[(((bb * 16 + hh) * 256 + ii) << 6) + dd] = (bf16)(x * 8.0f);
                    else if (sel == 1)
                        Cb[1048576 + (((bb * 16 + hh) * 256 + ii) << 6) + dd] = (bf16)x;
                    else
                        Cb[2097152 + ((((bb * 16 + hh) << 6) + dd) << 8) + ii] = (bf16)x;
                }
            }
        }
    }
}

// ---------------- fused attention (unchanged)
__global__ __launch_bounds__(256) void flash_kernel(
    const bf16* __restrict__ Qb, const bf16* __restrict__ Kb,
    const bf16* __restrict__ VT, const bf16* __restrict__ biasT,
    bf16* __restrict__ out)
{
    __shared__ __align__(16) char pls[32768];
    int t = threadIdx.x;
    int w = t >> 6, l = t & 63;
    int lr = l & 15, hi = l >> 4;
    int bh = blockIdx.x >> 2, iq = blockIdx.x & 3;
    int b = bh >> 4, h = bh & 15;
    int i0 = iq * 64 + w * 16;

    const bf16* Qp = Qb + (bh * 256 + i0 + lr) * 64 + hi * 8;
    bf16x8 qf0 = *(const bf16x8*)(Qp);
    bf16x8 qf1 = *(const bf16x8*)(Qp + 32);

    f32x4 acc[16];
    #pragma unroll
    for (int f = 0; f < 16; f++) acc[f] = (f32x4){0.f, 0.f, 0.f, 0.f};

    const bf16* Kp = Kb + (bh * 256 + lr) * 64 + hi * 8;
    #pragma unroll
    for (int f = 0; f < 16; f++) {
        bf16x8 kf0 = *(const bf16x8*)(Kp + f * 1024);
        bf16x8 kf1 = *(const bf16x8*)(Kp + f * 1024 + 32);
        acc[f] = __builtin_amdgcn_mfma_f32_16x16x32_bf16(qf0, kf0, acc[f], 0, 0, 0);
        acc[f] = __builtin_amdgcn_mfma_f32_16x16x32_bf16(qf1, kf1, acc[f], 0, 0, 0);
    }

    const bf16* bp = biasT + (bh * 256 + i0 + hi * 4) * 256 + lr;
    #pragma unroll
    for (int f = 0; f < 16; f++)
        #pragma unroll
        for (int q = 0; q < 4; q++)
            acc[f][q] += __bfloat162float(bp[q * 256 + f * 16]);

    float inv[4];
    #pragma unroll
    for (int q = 0; q < 4; q++) {
        float m = acc[0][q];
        #pragma unroll
        for (int f = 1; f < 16; f++) m = fmaxf(m, acc[f][q]);
        #pragma unroll
        for (int msk = 1; msk < 16; msk <<= 1) m = fmaxf(m, __shfl_xor(m, msk));
        float s = 0.f;
        #pragma unroll
        for (int f = 0; f < 16; f++) {
            float e = __expf(acc[f][q] - m);
            acc[f][q] = e;
            s += e;
        }
        #pragma unroll
        for (int msk = 1; msk < 16; msk <<= 1) s += __shfl_xor(s, msk);
        inv[q] = 1.f / s;
    }

    char* Pw = pls + w * 8192;
    #pragma unroll
    for (int f = 0; f < 16; f++) {
        int j = f * 16 + lr;
        int c = j >> 3, jo = j & 7;
        #pragma unroll
        for (int q = 0; q < 4; q++)
            *(bf16*)(Pw + c * 256 + (hi * 4 + q) * 16 + jo * 2) = (bf16)(acc[f][q] * inv[q]);
    }
    __syncthreads();

    const char* Pr = pls + w * 8192 + hi * 256 + lr * 16;
    const bf16* Vp = VT + (bh * 64 + lr) * 256 + hi * 8;
    #pragma unroll
    for (int n = 0; n < 4; n++) {
        f32x4 o = (f32x4){0.f, 0.f, 0.f, 0.f};
        #pragma unroll
        for (int ks = 0; ks < 8; ks++) {
            bf16x8 pa = *(const bf16x8*)(Pr + ks * 1024);
            bf16x8 vb = *(const bf16x8*)(Vp + n * 4096 + ks * 32);
            o = __builtin_amdgcn_mfma_f32_16x16x32_bf16(pa, vb, o, 0, 0, 0);
        }
        #pragma unroll
        for (int q = 0; q < 4; q++)
            out[(b * 256 + i0 + hi * 4 + q) * 1024 + h * 64 + n * 16 + lr] = (bf16)o[q];
    }
}

// ---------------- LN( add + bias + sum_s part[s] ), f32 out + optional bf16 out
__global__ __launch_bounds__(256) void ln_fused_kernel(
    const float* __restrict__ part, int S,
    const float* __restrict__ bias, const float* __restrict__ add,
    const float* __restrict__ g, const float* __restrict__ bta,
    float* __restrict__ out, bf16* __restrict__ ob)
{
    int row = blockIdx.x;
    int t = threadIdx.x;
    float v[4];
    float sum = 0.f;
    #pragma unroll
    for (int i = 0; i < 4; i++) {
        int c = t + i * 256;
        float x = add[row * 1024 + c] + bias[c];
        for (int s = 0; s < S; s++) x += part[s * 1048576 + row * 1024 + c];
        v[i] = x;
        sum += x;
    }
    __shared__ float red[8];
    #pragma unroll
    for (int off = 32; off; off >>= 1) sum += __shfl_xor(sum, off);
    if ((t & 63) == 0) red[t >> 6] = sum;
    __syncthreads();
    float mean = (red[0] + red[1] + red[2] + red[3]) * (1.f / 1024.f);
    float vs = 0.f;
    #pragma unroll
    for (int i = 0; i < 4; i++) { float d = v[i] - mean; vs += d * d; }
    #pragma unroll
    for (int off = 32; off; off >>= 1) vs += __shfl_xor(vs, off);
    if ((t & 63) == 0) red[4 + (t >> 6)] = vs;
    __syncthreads();
    float var = (red[4] + red[5] + red[6] + red[7]) * (1.f / 1024.f);
    float invs = rsqrtf(var + 1e-5f);
    #pragma unroll
    for (int i = 0; i < 4; i++) {
        int c = t + i * 256;
        float o = (v[i] - mean) * invs * g[c] + bta[c];
        out[row * 1024 + c] = o;
        if (ob) ob[row * 1024 + c] = (bf16)o;
    }
}

extern "C" void kernel_launch(void* const* d_in, const int* in_sizes, int n_in,
                              void* d_out, int out_size, void* d_ws, size_t ws_size,
                              hipStream_t stream)
{
    const float* nfeat  = (const float*)d_in[0];
    const int*   sp     = (const int*)  d_in[1];
    const float* rd     = (const float*)d_in[2];
    const float* table  = (const float*)d_in[3];
    const float* gmeans = (const float*)d_in[4];
    const float* gstds  = (const float*)d_in[5];
    const float* gmul   = (const float*)d_in[6];
    const float* gbias  = (const float*)d_in[7];
    const float* w1     = (const float*)d_in[8];
    const float* b1     = (const float*)d_in[9];
    const float* w2     = (const float*)d_in[10];
    const float* b2     = (const float*)d_in[11];
    const float* wq     = (const float*)d_in[12];
    const float* bq     = (const float*)d_in[13];
    const float* wk     = (const float*)d_in[14];
    const float* bk     = (const float*)d_in[15];
    const float* wv     = (const float*)d_in[16];
    const float* bv     = (const float*)d_in[17];
    const float* wo     = (const float*)d_in[18];
    const float* bo     = (const float*)d_in[19];
    const float* fw1    = (const float*)d_in[20];
    const float* fb1    = (const float*)d_in[21];
    const float* fw2    = (const float*)d_in[22];
    const float* fb2    = (const float*)d_in[23];
    const float* ln1g   = (const float*)d_in[24];
    const float* ln1b   = (const float*)d_in[25];
    const float* ln2g   = (const float*)d_in[26];
    const float* ln2b   = (const float*)d_in[27];

    const size_t MB = 1 << 20;
    char* cws = (char*)d_ws;
    // liveness-packed layout (ws >= 64MB):
    bf16*  biasT   = (bf16*)(cws);             // 0-8MB: bias [B,H,N,N]; later hiddenb
    bf16*  qkvb    = (bf16*)(cws + 8 * MB);    // 8-14MB: q|k [B,H,N,D], v^T [B,H,D,N]
    float* part    = (float*)(cws + 8 * MB);   // 8-24MB: split-K partials (after flash)
    bf16*  qkvT    = (bf16*)(cws + 16 * MB);   // 16-22MB (dead after QKV gemm)
    bf16*  woT     = (bf16*)(cws + 22 * MB);   // 22-24MB (dead after Wo gemm)
    bf16*  fw1T    = (bf16*)(cws + 24 * MB);   // 24-32MB
    bf16*  fw2T    = (bf16*)(cws + 32 * MB);   // 32-40MB
    float* x1      = (float*)(cws + 40 * MB);  // 40-44MB
    bf16*  nfeatb  = (bf16*)(cws + 44 * MB);   // 44-46MB
    bf16*  x1b     = (bf16*)(cws + 46 * MB);   // 46-48MB
    bf16*  attnob  = (bf16*)(cws + 48 * MB);   // 48-50MB
    float* bqkv    = (float*)(cws + 50 * MB);  // 12KB
    float* tw      = (float*)(cws + 50 * MB + 16384);
    bf16*  hiddenb = biasT;                    // [1024][4096] bf16 (after flash)

    setup_kernel<<<1037, 256, 0, stream>>>(nfeat, nfeatb, bq, bk, bv, bqkv,
                                           table, w1, tw);
    wt_all_kernel<<<12288, 256, 0, stream>>>(wq, wk, wv, wo, fw1, fw2,
                                             qkvT, woT, fw1T, fw2T);
    enc_kernel<<<1024, 256, 0, stream>>>(sp, rd, tw, gmeans, gstds, gmul, gbias,
                                         w1, b1, w2, b2, biasT);

    // QKV fused GEMM -> bf16 q/k/v^T
    gemm_bf16<<<dim3(48, 16), 256, 0, stream>>>(nfeatb, qkvT, bqkv, nullptr, qkvb,
                                                1024, 3072, 1024, 3);

    flash_kernel<<<256, 256, 0, stream>>>(qkvb, qkvb + 1048576, qkvb + 2097152,
                                          biasT, attnob);

    // Wo: split-K=2 -> partials ; LN1 folds (+bo, +nfeat, reduce)
    gemm_bf16<<<dim3(16, 16, 2), 256, 0, stream>>>(attnob, woT, bo, nullptr, part,
                                                   1024, 1024, 1024, 0);
    ln_fused_kernel<<<1024, 256, 0, stream>>>(part, 2, bo, nfeat, ln1g, ln1b, x1, x1b);

    // FFN1: direct (1024 blocks), ReLU -> bf16 hidden
    gemm_bf16<<<dim3(64, 16), 256, 0, stream>>>(x1b, fw1T, fb1, nullptr, hiddenb,
                                                1024, 4096, 1024, 2);

    // FFN2: split-K=4 -> partials ; LN2 folds (+fb2, +x1, reduce) -> d_out
    gemm_bf16<<<dim3(16, 16, 4), 256, 0, stream>>>(hiddenb, fw2T, fb2, nullptr, part,
                                                   1024, 1024, 4096, 0);
    ln_fused_kernel<<<1024, 256, 0, stream>>>(part, 4, fb2, x1, ln2g, ln2b,
                                              (float*)d_out, nullptr);
}